// Round 5
// baseline (4542.358 us; speedup 1.0000x reference)
//
#include <hip/hip_runtime.h>
#include <hip/hip_bf16.h>

// HeteroGATv2: 3 node types x 50000 nodes, 7 edge types x 800000 edges,
// 2 GATv2 layers (H=64), softmax head (4 classes) on node type 0.
//
// R5: two-pass BINNED scatter for the CSR build. R4's direct scatter wrote
// 370 MB to HBM (5.6M random 4B writes over 350K row-frontiers -> every 64B
// line evicted partially filled). Binning by 256-row buckets keeps only 1368
// frontier lines (~87KB, L2-resident) in pass 1 and gives pass 2 dense 16KB
// write regions -> write traffic ~= payload. Bucket offsets are free: they
// are P[b*256] (prefix sums of the fine histogram).
// Also: xl/xr linear transforms merged into one dispatch (blockIdx.y) with
// 16 nodes/block to amortize the weight LDS fill.
//
// Dtype-adaptive (proven in R2): detector decides bf16 vs f32 once.

#define N_NODES 50000
#define NEDGE   800000
#define HDIM    64
#define DIN     32
#define NROWS   (7 * N_NODES)              // 350000 global rows (type-major)
#define NBUCK   ((NROWS + 255) >> 8)       // 1368 buckets of 256 rows

typedef __hip_bfloat16 bf16;

__device__ __forceinline__ float ldf(const void* p, size_t i, int bf) {
    return bf ? __bfloat162float(((const bf16*)p)[i]) : ((const float*)p)[i];
}

// flag[0] = 1 if x is bf16, 0 if f32.
__global__ void detect_kernel(const unsigned short* __restrict__ x, int* __restrict__ flag)
{
    __shared__ int sbad[256];
    int bad = 0;
    for (int i = threadIdx.x; i < 4096; i += 256) {
        unsigned short u = x[i];
        int ex = (u >> 7) & 0xff;
        bool zero = (u & 0x7fffu) == 0;
        if (!zero && (ex < 80 || ex > 140)) bad++;
    }
    sbad[threadIdx.x] = bad;
    __syncthreads();
    for (int s = 128; s > 0; s >>= 1) {
        if (threadIdx.x < s) sbad[threadIdx.x] += sbad[threadIdx.x + s];
        __syncthreads();
    }
    if (threadIdx.x == 0) flag[0] = (sbad[0] < 64) ? 1 : 0;
}

// ---------------- CSR build ----------------

__global__ __launch_bounds__(256) void hist_kernel(const int* __restrict__ edges,
                                                   int* __restrict__ cnt, int ntypes)
{
    int g = blockIdx.x * 256 + threadIdx.x;
    if (g >= ntypes * NEDGE) return;
    int t = g / NEDGE, i = g - t * NEDGE;
    int d = edges[(size_t)t * 2 * NEDGE + NEDGE + i];
    atomicAdd(&cnt[t * N_NODES + d], 1);
}

__global__ __launch_bounds__(256) void scanA_kernel(const int* __restrict__ cnt,
                                                    int* __restrict__ bsums, int n)
{
    __shared__ int lds[256];
    int tid = threadIdx.x;
    int base = blockIdx.x * 2048 + tid * 8;
    int s = 0;
    #pragma unroll
    for (int k = 0; k < 8; ++k) { int i = base + k; if (i < n) s += cnt[i]; }
    lds[tid] = s;
    __syncthreads();
    for (int o = 128; o > 0; o >>= 1) {
        if (tid < o) lds[tid] += lds[tid + o];
        __syncthreads();
    }
    if (tid == 0) bsums[blockIdx.x] = lds[0];
}

__global__ __launch_bounds__(256) void scanB_kernel(const int* __restrict__ bsums,
                                                    int* __restrict__ boffs, int nb,
                                                    int* __restrict__ P, int n)
{
    __shared__ int lds[256];
    int tid = threadIdx.x;
    int v = (tid < nb) ? bsums[tid] : 0;
    lds[tid] = v;
    __syncthreads();
    for (int off = 1; off < 256; off <<= 1) {
        int t2 = (tid >= off) ? lds[tid - off] : 0;
        __syncthreads();
        lds[tid] += t2;
        __syncthreads();
    }
    if (tid < nb) boffs[tid] = lds[tid] - v;
    if (tid == 255) P[n] = lds[255];
}

__global__ __launch_bounds__(256) void scanC_kernel(const int* __restrict__ cnt,
                                                    const int* __restrict__ boffs,
                                                    int* __restrict__ P,
                                                    int* __restrict__ cursor, int n)
{
    __shared__ int lds[256];
    int tid = threadIdx.x;
    int base = blockIdx.x * 2048 + tid * 8;
    int v[8];
    int s = 0;
    #pragma unroll
    for (int k = 0; k < 8; ++k) {
        int i = base + k;
        int c = (i < n) ? cnt[i] : 0;
        v[k] = s;
        s += c;
    }
    lds[tid] = s;
    __syncthreads();
    for (int off = 1; off < 256; off <<= 1) {
        int t2 = (tid >= off) ? lds[tid - off] : 0;
        __syncthreads();
        lds[tid] += t2;
        __syncthreads();
    }
    int off0 = boffs[blockIdx.x] + (lds[tid] - s);
    #pragma unroll
    for (int k = 0; k < 8; ++k) {
        int i = base + k;
        if (i < n) { int val = off0 + v[k]; P[i] = val; cursor[i] = val; }
    }
}

// bucket frontier init: bcur[b] = P[b*256]
__global__ __launch_bounds__(256) void bcur_init_kernel(const int* __restrict__ P,
                                                        int* __restrict__ bcur)
{
    int b = blockIdx.x * 256 + threadIdx.x;
    if (b < NBUCK) bcur[b] = P[b << 8];
}

// pass 1: partition edges into 256-row buckets; payload = (r&255)<<16 | src
__global__ __launch_bounds__(256) void pass1_kernel(const int* __restrict__ edges,
                                                    int* __restrict__ bcur,
                                                    unsigned* __restrict__ buf)
{
    int g = blockIdx.x * 256 + threadIdx.x;
    if (g >= 7 * NEDGE) return;
    int t = g / NEDGE, i = g - t * NEDGE;
    int s = edges[(size_t)t * 2 * NEDGE + i];
    int d = edges[(size_t)t * 2 * NEDGE + NEDGE + i];
    int r = t * N_NODES + d;
    int pos = atomicAdd(&bcur[r >> 8], 1);
    buf[pos] = ((unsigned)(r & 255) << 16) | (unsigned)s;
}

// pass 2: one block per bucket; place entries at fine cursors (dense 16KB region)
__global__ __launch_bounds__(256) void pass2_kernel(const unsigned* __restrict__ buf,
                                                    const int* __restrict__ P,
                                                    int* __restrict__ cursor,
                                                    int* __restrict__ col_src)
{
    int b = blockIdx.x;
    int start = P[b << 8];
    int rend = (b + 1) << 8; if (rend > NROWS) rend = NROWS;
    int end = P[rend];
    for (int i = start + threadIdx.x; i < end; i += 256) {
        unsigned v = buf[i];
        int r = (b << 8) | (int)(v >> 16);
        int s = (int)(v & 0xffffu);
        int pos = atomicAdd(&cursor[r], 1);
        col_src[pos] = s;
    }
}

// fallback direct scatter (single type)
__global__ __launch_bounds__(256) void scatter1_kernel(const int* __restrict__ et,
                                                       int* __restrict__ cursor,
                                                       int* __restrict__ col_src)
{
    int i = blockIdx.x * 256 + threadIdx.x;
    if (i >= NEDGE) return;
    int s = et[i], d = et[NEDGE + i];
    int pos = atomicAdd(&cursor[d], 1);
    col_src[pos] = s;
}

// ---------------- linear transforms (xl & xr in one dispatch) ----------------

__global__ __launch_bounds__(256) void lin_d32_kernel(
    const void* fLb, const void* fLf, const void* fRb, const void* fRf,
    const void* wLb, const void* wLf, const void* wRb, const void* wRf,
    const void* bLb, const void* bLf, const void* bRb, const void* bRf,
    const int* __restrict__ flag, float* __restrict__ xl, float* __restrict__ xr)
{
    __shared__ float sW[DIN * HDIM];
    __shared__ float sb[HDIM];
    int bf = flag[0];
    int side = blockIdx.y;
    const void* W    = side ? (bf ? wRb : wRf) : (bf ? wLb : wLf);
    const void* b    = side ? (bf ? bRb : bRf) : (bf ? bLb : bLf);
    const void* feat = side ? (bf ? fRb : fRf) : (bf ? fLb : fLf);
    float* out = side ? xr : xl;
    int tid = threadIdx.x;
    for (int k = tid; k < DIN * HDIM; k += 256) sW[k] = ldf(W, k, bf);
    if (tid < HDIM) sb[tid] = ldf(b, tid, bf);
    __syncthreads();
    int h = tid & 63;
    int slot = tid >> 6;
    int base = blockIdx.x * 16;
    for (int nn = slot; nn < 16; nn += 4) {
        int node = base + nn;
        if (node >= N_NODES) break;
        float acc = sb[h];
        #pragma unroll
        for (int d = 0; d < DIN; ++d)
            acc += ldf(feat, (size_t)node * DIN + d, bf) * sW[d * HDIM + h];
        out[(size_t)node * HDIM + h] = acc;
    }
}

__global__ __launch_bounds__(256) void lin_d64_kernel(
    const float* __restrict__ fL, const float* __restrict__ fR,
    const void* wLb, const void* wLf, const void* wRb, const void* wRf,
    const void* bLb, const void* bLf, const void* bRb, const void* bRf,
    const int* __restrict__ flag, float* __restrict__ xl, float* __restrict__ xr)
{
    __shared__ float sW[HDIM * HDIM];
    __shared__ float sb[HDIM];
    int bf = flag[0];
    int side = blockIdx.y;
    const void* W = side ? (bf ? wRb : wRf) : (bf ? wLb : wLf);
    const void* b = side ? (bf ? bRb : bRf) : (bf ? bLb : bLf);
    const float* feat = side ? fR : fL;
    float* out = side ? xr : xl;
    int tid = threadIdx.x;
    for (int k = tid; k < HDIM * HDIM; k += 256) sW[k] = ldf(W, k, bf);
    if (tid < HDIM) sb[tid] = ldf(b, tid, bf);
    __syncthreads();
    int h = tid & 63;
    int slot = tid >> 6;
    int base = blockIdx.x * 16;
    for (int nn = slot; nn < 16; nn += 4) {
        int node = base + nn;
        if (node >= N_NODES) break;
        float acc = sb[h];
        const float4* f4 = (const float4*)(feat + (size_t)node * HDIM);
        #pragma unroll
        for (int k = 0; k < 16; ++k) {
            float4 a = f4[k];
            acc += a.x * sW[(4*k+0) * HDIM + h] + a.y * sW[(4*k+1) * HDIM + h]
                 + a.z * sW[(4*k+2) * HDIM + h] + a.w * sW[(4*k+3) * HDIM + h];
        }
        out[(size_t)node * HDIM + h] = acc;
    }
}

// ---------------- fused GATv2 attention: one wave per dst node ----------------
__global__ __launch_bounds__(256) void gat_row_kernel(
    const int* __restrict__ rowptr, const int* __restrict__ col_src,
    const float* __restrict__ xl, const float* __restrict__ xr,
    const void* ab, const void* af, const int* __restrict__ flag,
    float* __restrict__ hn)
{
    int bf = flag[0];
    const void* att = bf ? ab : af;
    int wave = threadIdx.x >> 6;
    int lane = threadIdx.x & 63;
    int d = blockIdx.x * 4 + wave;
    if (d >= N_NODES) return;
    int rs = rowptr[d], re = rowptr[d + 1];
    if (re <= rs) return;

    float att_h = ldf(att, lane, bf);
    float xr_h = xr[(size_t)d * HDIM + lane];

    float m = -1e30f, s = 0.f, acc = 0.f;
    for (int cs = rs; cs < re; cs += 64) {
        int cnt = min(64, re - cs);
        int src_lane = (lane < cnt) ? col_src[cs + lane] : 0;
        float e_reg = -1e30f;
        for (int j = 0; j < cnt; ++j) {
            int src_j = __shfl(src_lane, j, 64);
            float v = xl[(size_t)src_j * HDIM + lane] + xr_h;
            v = v > 0.f ? v : 0.2f * v;
            float t = att_h * v;
            #pragma unroll
            for (int o = 32; o > 0; o >>= 1) t += __shfl_xor(t, o, 64);
            if (lane == j) e_reg = t;
        }
        float cm = e_reg;
        #pragma unroll
        for (int o = 32; o > 0; o >>= 1) cm = fmaxf(cm, __shfl_xor(cm, o, 64));
        if (cm > m) {
            float scale = __expf(m - cm);
            s *= scale; acc *= scale; m = cm;
        }
        for (int j = 0; j < cnt; ++j) {
            float ej = __shfl(e_reg, j, 64);
            float w = __expf(ej - m);
            s += w;
            int src_j = __shfl(src_lane, j, 64);
            acc += w * xl[(size_t)src_j * HDIM + lane];
        }
    }
    hn[(size_t)d * HDIM + lane] += acc / (s + 1e-16f);
}

// ---------------- epilogue ----------------

__global__ void bsum_kernel(const void* __restrict__ bias, const int* __restrict__ flag,
                            float* __restrict__ bsum)
{
    int bf = flag[0];
    int idx = threadIdx.x;  // 192 = 3*64
    if (idx >= 192) return;
    int nt = idx >> 6, h = idx & 63;
    float v;
    if (nt == 0)      v = ldf(bias, 0*64+h, bf) + ldf(bias, 1*64+h, bf) + ldf(bias, 4*64+h, bf);
    else if (nt == 1) v = ldf(bias, 2*64+h, bf) + ldf(bias, 5*64+h, bf);
    else              v = ldf(bias, 3*64+h, bf) + ldf(bias, 6*64+h, bf);
    bsum[idx] = v;
}

__global__ __launch_bounds__(256) void relu_kernel(
    const float* __restrict__ hn, const float* __restrict__ bsum,
    float* __restrict__ h)
{
    size_t idx = (size_t)blockIdx.x * 256 + threadIdx.x;
    if (idx >= (size_t)3 * N_NODES * HDIM) return;
    int nt = (int)(idx / ((size_t)N_NODES * HDIM));
    int hh = (int)(idx & 63);
    float v = hn[idx] + bsum[nt * 64 + hh];
    h[idx] = v > 0.f ? v : 0.f;
}

__global__ __launch_bounds__(256) void head_kernel(
    const float* __restrict__ h0, const void* __restrict__ Wout,
    const void* __restrict__ bout, const int* __restrict__ flag,
    void* __restrict__ out)
{
    __shared__ float sW[64 * 4];
    __shared__ float sb[4];
    int bf = flag[0];
    int tid = threadIdx.x;
    sW[tid] = ldf(Wout, tid, bf);
    if (tid < 4) sb[tid] = ldf(bout, tid, bf);
    __syncthreads();
    int i = blockIdx.x * 256 + tid;
    if (i >= N_NODES) return;
    float l0 = sb[0], l1 = sb[1], l2 = sb[2], l3 = sb[3];
    const float4* p = (const float4*)(h0 + (size_t)i * HDIM);
    #pragma unroll
    for (int k = 0; k < 16; ++k) {
        float4 a = p[k];
        int d = 4 * k;
        l0 += a.x * sW[d*4+0] + a.y * sW[(d+1)*4+0] + a.z * sW[(d+2)*4+0] + a.w * sW[(d+3)*4+0];
        l1 += a.x * sW[d*4+1] + a.y * sW[(d+1)*4+1] + a.z * sW[(d+2)*4+1] + a.w * sW[(d+3)*4+1];
        l2 += a.x * sW[d*4+2] + a.y * sW[(d+1)*4+2] + a.z * sW[(d+2)*4+2] + a.w * sW[(d+3)*4+2];
        l3 += a.x * sW[d*4+3] + a.y * sW[(d+1)*4+3] + a.z * sW[(d+2)*4+3] + a.w * sW[(d+3)*4+3];
    }
    float m = fmaxf(fmaxf(l0, l1), fmaxf(l2, l3));
    float e0 = __expf(l0 - m), e1 = __expf(l1 - m), e2 = __expf(l2 - m), e3 = __expf(l3 - m);
    float inv = 1.f / (e0 + e1 + e2 + e3);
    if (bf) {
        bf16* o = (bf16*)out;
        o[(size_t)4*i + 0] = __float2bfloat16(e0 * inv);
        o[(size_t)4*i + 1] = __float2bfloat16(e1 * inv);
        o[(size_t)4*i + 2] = __float2bfloat16(e2 * inv);
        o[(size_t)4*i + 3] = __float2bfloat16(e3 * inv);
    } else {
        float* o = (float*)out;
        o[(size_t)4*i + 0] = e0 * inv;
        o[(size_t)4*i + 1] = e1 * inv;
        o[(size_t)4*i + 2] = e2 * inv;
        o[(size_t)4*i + 3] = e3 * inv;
    }
}

struct P2 { const void* b; const void* f; };
static inline P2 off2(const void* base, size_t elem) {
    P2 r;
    r.b = (const void*)((const bf16*)base + elem);
    r.f = (const void*)((const float*)base + elem);
    return r;
}

extern "C" void kernel_launch(void* const* d_in, const int* in_sizes, int n_in,
                              void* d_out, int out_size, void* d_ws, size_t ws_size,
                              hipStream_t stream)
{
    const void* x     = d_in[0];
    const int*  edges = (const int*)d_in[1];
    const void* Wl0 = d_in[2];
    const void* Wr0 = d_in[3];
    const void* bl0 = d_in[4];
    const void* br0 = d_in[5];
    const void* att0 = d_in[6];
    const void* bias0 = d_in[7];
    const void* Wl1 = d_in[8];
    const void* Wr1 = d_in[9];
    const void* bl1 = d_in[10];
    const void* br1 = d_in[11];
    const void* att1 = d_in[12];
    const void* bias1 = d_in[13];
    const void* Wout = d_in[14];
    const void* bout = d_in[15];

    const int SRCt[7] = {0, 1, 1, 1, 2, 2, 2};
    const int DSTt[7] = {0, 0, 1, 2, 0, 1, 2};

    // ---- workspace layout ----
    float* h3  = (float*)d_ws;                                  // 3*N*H
    float* hn3 = h3 + (size_t)3 * N_NODES * HDIM;               // 3*N*H (38.4 MB)
    float* xl  = hn3 + (size_t)3 * N_NODES * HDIM;              // N*H
    float* xr  = xl + (size_t)N_NODES * HDIM;                   // N*H
    char* tail = (char*)(xr + (size_t)N_NODES * HDIM);

    size_t fixed = (size_t)tail - (size_t)d_ws;
    size_t need_full = fixed + ((size_t)NROWS + 1) * 4 + (size_t)7 * NEDGE * 4
                     + 2 * 256 * 4 + 192 * 4 + 4 + 2 * (size_t)N_NODES * 4 + 256;
    bool full = ws_size >= need_full;
    int NT = full ? 7 : 1;

    int* P        = (int*)tail;                                 // NT*N+1
    int* col_src  = P + ((size_t)NT * N_NODES + 1);             // NT*E
    int* bsums    = col_src + (size_t)NT * NEDGE;               // 256
    int* boffs    = bsums + 256;                                // 256
    float* bsum   = (float*)(boffs + 256);                      // 192
    int* flag     = (int*)(bsum + 192);                         // 1
    int* cnt;
    int* cursor;
    int* bcur = nullptr;
    unsigned* buf = nullptr;
    if (full) {
        // CSR build strictly precedes all hn3 use (stream-ordered) -> alias
        cnt    = (int*)hn3;                                     // NROWS (1.4 MB)
        cursor = cnt + NROWS;                                   // NROWS (1.4 MB)
        bcur   = cursor + NROWS;                                // NBUCK
        buf    = (unsigned*)(bcur + NBUCK + 64);                // 7E (22.4 MB) -> 25.2 < 38.4 MB
    } else {
        cnt = flag + 1;                                         // N
        cursor = cnt + N_NODES;                                 // N
    }

    dim3 blk(256);
    int gLin  = (N_NODES + 15) / 16;                            // 3125
    int gRow  = (N_NODES + 3) / 4;
    int gRelu = (int)(((size_t)3 * N_NODES * HDIM + 255) / 256);
    int gHead = (N_NODES + 255) / 256;

    detect_kernel<<<1, 256, 0, stream>>>((const unsigned short*)x, flag);

    if (full) {
        int n = NROWS;
        int nb = (n + 2047) / 2048;                  // 171
        int gE7 = (7 * NEDGE + 255) / 256;
        hipMemsetAsync(cnt, 0, (size_t)n * sizeof(int), stream);
        hist_kernel<<<gE7, blk, 0, stream>>>(edges, cnt, 7);
        scanA_kernel<<<nb, blk, 0, stream>>>(cnt, bsums, n);
        scanB_kernel<<<1, blk, 0, stream>>>(bsums, boffs, nb, P, n);
        scanC_kernel<<<nb, blk, 0, stream>>>(cnt, boffs, P, cursor, n);
        bcur_init_kernel<<<(NBUCK + 255) / 256, blk, 0, stream>>>(P, bcur);
        pass1_kernel<<<gE7, blk, 0, stream>>>(edges, bcur, buf);
        pass2_kernel<<<NBUCK, blk, 0, stream>>>(buf, P, cursor, col_src);
    }

    for (int layer = 0; layer < 2; ++layer) {
        const void* Wl = layer ? Wl1 : Wl0;
        const void* Wr = layer ? Wr1 : Wr0;
        const void* bl = layer ? bl1 : bl0;
        const void* br = layer ? br1 : br0;
        const void* at = layer ? att1 : att0;
        const void* bi = layer ? bias1 : bias0;

        hipMemsetAsync(hn3, 0, (size_t)3 * N_NODES * HDIM * sizeof(float), stream);
        bsum_kernel<<<1, 192, 0, stream>>>(bi, flag, bsum);

        for (int t = 0; t < 7; ++t) {
            const int* rp;
            const int* cs;
            if (full) {
                rp = P + (size_t)t * N_NODES;
                cs = col_src;    // P holds GLOBAL positions into col_src
            } else {
                const int* et = edges + (size_t)t * 2 * NEDGE;
                int n = N_NODES;
                int nb = (n + 2047) / 2048;          // 25
                int gE1 = (NEDGE + 255) / 256;
                hipMemsetAsync(cnt, 0, (size_t)n * sizeof(int), stream);
                hist_kernel<<<gE1, blk, 0, stream>>>(et, cnt, 1);
                scanA_kernel<<<nb, blk, 0, stream>>>(cnt, bsums, n);
                scanB_kernel<<<1, blk, 0, stream>>>(bsums, boffs, nb, P, n);
                scanC_kernel<<<nb, blk, 0, stream>>>(cnt, boffs, P, cursor, n);
                scatter1_kernel<<<gE1, blk, 0, stream>>>(et, cursor, col_src);
                rp = P;
                cs = col_src;
            }

            if (layer == 0) {
                P2 fs = off2(x, (size_t)SRCt[t] * N_NODES * DIN);
                P2 fd = off2(x, (size_t)DSTt[t] * N_NODES * DIN);
                P2 wl = off2(Wl, (size_t)t * DIN * HDIM);
                P2 wr = off2(Wr, (size_t)t * DIN * HDIM);
                P2 bL = off2(bl, (size_t)t * HDIM);
                P2 bR = off2(br, (size_t)t * HDIM);
                lin_d32_kernel<<<dim3(gLin, 2), blk, 0, stream>>>(
                    fs.b, fs.f, fd.b, fd.f, wl.b, wl.f, wr.b, wr.f,
                    bL.b, bL.f, bR.b, bR.f, flag, xl, xr);
            } else {
                P2 wl = off2(Wl, (size_t)t * HDIM * HDIM);
                P2 wr = off2(Wr, (size_t)t * HDIM * HDIM);
                P2 bL = off2(bl, (size_t)t * HDIM);
                P2 bR = off2(br, (size_t)t * HDIM);
                lin_d64_kernel<<<dim3(gLin, 2), blk, 0, stream>>>(
                    h3 + (size_t)SRCt[t] * N_NODES * HDIM,
                    h3 + (size_t)DSTt[t] * N_NODES * HDIM,
                    wl.b, wl.f, wr.b, wr.f, bL.b, bL.f, bR.b, bR.f, flag, xl, xr);
            }

            P2 a2 = off2(at, (size_t)t * HDIM);
            gat_row_kernel<<<gRow, blk, 0, stream>>>(rp, cs, xl, xr,
                                                     a2.b, a2.f, flag,
                                                     hn3 + (size_t)DSTt[t] * N_NODES * HDIM);
        }
        relu_kernel<<<gRelu, blk, 0, stream>>>(hn3, bsum, h3);
    }

    head_kernel<<<gHead, blk, 0, stream>>>(h3, Wout, bout, flag, d_out);
}

// Round 6
// 3055.108 us; speedup vs baseline: 1.4868x; 1.4868x over previous
//
#include <hip/hip_runtime.h>
#include <hip/hip_bf16.h>

// HeteroGATv2: 3 node types x 50000 nodes, 7 edge types x 800000 edges,
// 2 GATv2 layers (H=64), softmax head (4 classes) on node type 0.
//
// R6: binned scatter with 16-row buckets (21875 buckets). R5's 256-row
// buckets (1368) hit atomic-contention serialization: 5.6M atomics over 1368
// cursors = chains of 4096 same-address device atomics (~475ns each) ->
// pass1 1940us. 16-row buckets cut chains to 256 while the 1.4MB frontier
// stays L2-resident (write traffic ~= payload). pass2 keeps the 16 fine
// cursors in LDS (no global cursor array).
//
// Dtype-adaptive (proven in R2): detector decides bf16 vs f32 once.

#define N_NODES 50000
#define NEDGE   800000
#define HDIM    64
#define DIN     32
#define NROWS   (7 * N_NODES)              // 350000 global rows (type-major)
#define BROWS   16                         // rows per bucket
#define NBUCK   (NROWS / BROWS)            // 21875 buckets (exact)

typedef __hip_bfloat16 bf16;

__device__ __forceinline__ float ldf(const void* p, size_t i, int bf) {
    return bf ? __bfloat162float(((const bf16*)p)[i]) : ((const float*)p)[i];
}

// flag[0] = 1 if x is bf16, 0 if f32.
__global__ void detect_kernel(const unsigned short* __restrict__ x, int* __restrict__ flag)
{
    __shared__ int sbad[256];
    int bad = 0;
    for (int i = threadIdx.x; i < 4096; i += 256) {
        unsigned short u = x[i];
        int ex = (u >> 7) & 0xff;
        bool zero = (u & 0x7fffu) == 0;
        if (!zero && (ex < 80 || ex > 140)) bad++;
    }
    sbad[threadIdx.x] = bad;
    __syncthreads();
    for (int s = 128; s > 0; s >>= 1) {
        if (threadIdx.x < s) sbad[threadIdx.x] += sbad[threadIdx.x + s];
        __syncthreads();
    }
    if (threadIdx.x == 0) flag[0] = (sbad[0] < 64) ? 1 : 0;
}

// ---------------- CSR build ----------------

__global__ __launch_bounds__(256) void hist_kernel(const int* __restrict__ edges,
                                                   int* __restrict__ cnt, int ntypes)
{
    int g = blockIdx.x * 256 + threadIdx.x;
    if (g >= ntypes * NEDGE) return;
    int t = g / NEDGE, i = g - t * NEDGE;
    int d = edges[(size_t)t * 2 * NEDGE + NEDGE + i];
    atomicAdd(&cnt[t * N_NODES + d], 1);
}

__global__ __launch_bounds__(256) void scanA_kernel(const int* __restrict__ cnt,
                                                    int* __restrict__ bsums, int n)
{
    __shared__ int lds[256];
    int tid = threadIdx.x;
    int base = blockIdx.x * 2048 + tid * 8;
    int s = 0;
    #pragma unroll
    for (int k = 0; k < 8; ++k) { int i = base + k; if (i < n) s += cnt[i]; }
    lds[tid] = s;
    __syncthreads();
    for (int o = 128; o > 0; o >>= 1) {
        if (tid < o) lds[tid] += lds[tid + o];
        __syncthreads();
    }
    if (tid == 0) bsums[blockIdx.x] = lds[0];
}

__global__ __launch_bounds__(256) void scanB_kernel(const int* __restrict__ bsums,
                                                    int* __restrict__ boffs, int nb,
                                                    int* __restrict__ P, int n)
{
    __shared__ int lds[256];
    int tid = threadIdx.x;
    int v = (tid < nb) ? bsums[tid] : 0;
    lds[tid] = v;
    __syncthreads();
    for (int off = 1; off < 256; off <<= 1) {
        int t2 = (tid >= off) ? lds[tid - off] : 0;
        __syncthreads();
        lds[tid] += t2;
        __syncthreads();
    }
    if (tid < nb) boffs[tid] = lds[tid] - v;
    if (tid == 255) P[n] = lds[255];
}

__global__ __launch_bounds__(256) void scanC_kernel(const int* __restrict__ cnt,
                                                    const int* __restrict__ boffs,
                                                    int* __restrict__ P,
                                                    int* __restrict__ cursor, int n)
{
    __shared__ int lds[256];
    int tid = threadIdx.x;
    int base = blockIdx.x * 2048 + tid * 8;
    int v[8];
    int s = 0;
    #pragma unroll
    for (int k = 0; k < 8; ++k) {
        int i = base + k;
        int c = (i < n) ? cnt[i] : 0;
        v[k] = s;
        s += c;
    }
    lds[tid] = s;
    __syncthreads();
    for (int off = 1; off < 256; off <<= 1) {
        int t2 = (tid >= off) ? lds[tid - off] : 0;
        __syncthreads();
        lds[tid] += t2;
        __syncthreads();
    }
    int off0 = boffs[blockIdx.x] + (lds[tid] - s);
    #pragma unroll
    for (int k = 0; k < 8; ++k) {
        int i = base + k;
        if (i < n) { int val = off0 + v[k]; P[i] = val; cursor[i] = val; }
    }
}

// bucket frontier init: bcur[b] = P[b*BROWS]
__global__ __launch_bounds__(256) void bcur_init_kernel(const int* __restrict__ P,
                                                        int* __restrict__ bcur)
{
    int b = blockIdx.x * 256 + threadIdx.x;
    if (b < NBUCK) bcur[b] = P[b * BROWS];
}

// pass 1: partition edges into 16-row buckets; payload = (r&15)<<16 | src
__global__ __launch_bounds__(256) void pass1_kernel(const int* __restrict__ edges,
                                                    int* __restrict__ bcur,
                                                    unsigned* __restrict__ buf)
{
    int g = blockIdx.x * 256 + threadIdx.x;
    if (g >= 7 * NEDGE) return;
    int t = g / NEDGE, i = g - t * NEDGE;
    int s = edges[(size_t)t * 2 * NEDGE + i];
    int d = edges[(size_t)t * 2 * NEDGE + NEDGE + i];
    int r = t * N_NODES + d;
    int pos = atomicAdd(&bcur[r >> 4], 1);
    buf[pos] = ((unsigned)(r & 15) << 16) | (unsigned)s;
}

// pass 2: one block per bucket; 16 fine row-cursors in LDS; dense 16KB region
__global__ __launch_bounds__(256) void pass2_kernel(const unsigned* __restrict__ buf,
                                                    const int* __restrict__ P,
                                                    int* __restrict__ col_src)
{
    __shared__ int scur[BROWS];
    int b = blockIdx.x;
    int r0 = b * BROWS;
    if (threadIdx.x < BROWS) scur[threadIdx.x] = P[r0 + threadIdx.x];
    __syncthreads();
    int start = P[r0];
    int end = P[r0 + BROWS];
    for (int i = start + threadIdx.x; i < end; i += 256) {
        unsigned v = buf[i];
        int ri = (int)(v >> 16);
        int s = (int)(v & 0xffffu);
        int pos = atomicAdd(&scur[ri], 1);
        col_src[pos] = s;
    }
}

// fallback direct scatter (single type)
__global__ __launch_bounds__(256) void scatter1_kernel(const int* __restrict__ et,
                                                       int* __restrict__ cursor,
                                                       int* __restrict__ col_src)
{
    int i = blockIdx.x * 256 + threadIdx.x;
    if (i >= NEDGE) return;
    int s = et[i], d = et[NEDGE + i];
    int pos = atomicAdd(&cursor[d], 1);
    col_src[pos] = s;
}

// ---------------- linear transforms (xl & xr in one dispatch) ----------------

__global__ __launch_bounds__(256) void lin_d32_kernel(
    const void* fLb, const void* fLf, const void* fRb, const void* fRf,
    const void* wLb, const void* wLf, const void* wRb, const void* wRf,
    const void* bLb, const void* bLf, const void* bRb, const void* bRf,
    const int* __restrict__ flag, float* __restrict__ xl, float* __restrict__ xr)
{
    __shared__ float sW[DIN * HDIM];
    __shared__ float sb[HDIM];
    int bf = flag[0];
    int side = blockIdx.y;
    const void* W    = side ? (bf ? wRb : wRf) : (bf ? wLb : wLf);
    const void* b    = side ? (bf ? bRb : bRf) : (bf ? bLb : bLf);
    const void* feat = side ? (bf ? fRb : fRf) : (bf ? fLb : fLf);
    float* out = side ? xr : xl;
    int tid = threadIdx.x;
    for (int k = tid; k < DIN * HDIM; k += 256) sW[k] = ldf(W, k, bf);
    if (tid < HDIM) sb[tid] = ldf(b, tid, bf);
    __syncthreads();
    int h = tid & 63;
    int slot = tid >> 6;
    int base = blockIdx.x * 16;
    for (int nn = slot; nn < 16; nn += 4) {
        int node = base + nn;
        if (node >= N_NODES) break;
        float acc = sb[h];
        #pragma unroll
        for (int d = 0; d < DIN; ++d)
            acc += ldf(feat, (size_t)node * DIN + d, bf) * sW[d * HDIM + h];
        out[(size_t)node * HDIM + h] = acc;
    }
}

__global__ __launch_bounds__(256) void lin_d64_kernel(
    const float* __restrict__ fL, const float* __restrict__ fR,
    const void* wLb, const void* wLf, const void* wRb, const void* wRf,
    const void* bLb, const void* bLf, const void* bRb, const void* bRf,
    const int* __restrict__ flag, float* __restrict__ xl, float* __restrict__ xr)
{
    __shared__ float sW[HDIM * HDIM];
    __shared__ float sb[HDIM];
    int bf = flag[0];
    int side = blockIdx.y;
    const void* W = side ? (bf ? wRb : wRf) : (bf ? wLb : wLf);
    const void* b = side ? (bf ? bRb : bRf) : (bf ? bLb : bLf);
    const float* feat = side ? fR : fL;
    float* out = side ? xr : xl;
    int tid = threadIdx.x;
    for (int k = tid; k < HDIM * HDIM; k += 256) sW[k] = ldf(W, k, bf);
    if (tid < HDIM) sb[tid] = ldf(b, tid, bf);
    __syncthreads();
    int h = tid & 63;
    int slot = tid >> 6;
    int base = blockIdx.x * 16;
    for (int nn = slot; nn < 16; nn += 4) {
        int node = base + nn;
        if (node >= N_NODES) break;
        float acc = sb[h];
        const float4* f4 = (const float4*)(feat + (size_t)node * HDIM);
        #pragma unroll
        for (int k = 0; k < 16; ++k) {
            float4 a = f4[k];
            acc += a.x * sW[(4*k+0) * HDIM + h] + a.y * sW[(4*k+1) * HDIM + h]
                 + a.z * sW[(4*k+2) * HDIM + h] + a.w * sW[(4*k+3) * HDIM + h];
        }
        out[(size_t)node * HDIM + h] = acc;
    }
}

// ---------------- fused GATv2 attention: one wave per dst node ----------------
__global__ __launch_bounds__(256) void gat_row_kernel(
    const int* __restrict__ rowptr, const int* __restrict__ col_src,
    const float* __restrict__ xl, const float* __restrict__ xr,
    const void* ab, const void* af, const int* __restrict__ flag,
    float* __restrict__ hn)
{
    int bf = flag[0];
    const void* att = bf ? ab : af;
    int wave = threadIdx.x >> 6;
    int lane = threadIdx.x & 63;
    int d = blockIdx.x * 4 + wave;
    if (d >= N_NODES) return;
    int rs = rowptr[d], re = rowptr[d + 1];
    if (re <= rs) return;

    float att_h = ldf(att, lane, bf);
    float xr_h = xr[(size_t)d * HDIM + lane];

    float m = -1e30f, s = 0.f, acc = 0.f;
    for (int cs = rs; cs < re; cs += 64) {
        int cnt = min(64, re - cs);
        int src_lane = (lane < cnt) ? col_src[cs + lane] : 0;
        float e_reg = -1e30f;
        for (int j = 0; j < cnt; ++j) {
            int src_j = __shfl(src_lane, j, 64);
            float v = xl[(size_t)src_j * HDIM + lane] + xr_h;
            v = v > 0.f ? v : 0.2f * v;
            float t = att_h * v;
            #pragma unroll
            for (int o = 32; o > 0; o >>= 1) t += __shfl_xor(t, o, 64);
            if (lane == j) e_reg = t;
        }
        float cm = e_reg;
        #pragma unroll
        for (int o = 32; o > 0; o >>= 1) cm = fmaxf(cm, __shfl_xor(cm, o, 64));
        if (cm > m) {
            float scale = __expf(m - cm);
            s *= scale; acc *= scale; m = cm;
        }
        for (int j = 0; j < cnt; ++j) {
            float ej = __shfl(e_reg, j, 64);
            float w = __expf(ej - m);
            s += w;
            int src_j = __shfl(src_lane, j, 64);
            acc += w * xl[(size_t)src_j * HDIM + lane];
        }
    }
    hn[(size_t)d * HDIM + lane] += acc / (s + 1e-16f);
}

// ---------------- epilogue ----------------

__global__ void bsum_kernel(const void* __restrict__ bias, const int* __restrict__ flag,
                            float* __restrict__ bsum)
{
    int bf = flag[0];
    int idx = threadIdx.x;  // 192 = 3*64
    if (idx >= 192) return;
    int nt = idx >> 6, h = idx & 63;
    float v;
    if (nt == 0)      v = ldf(bias, 0*64+h, bf) + ldf(bias, 1*64+h, bf) + ldf(bias, 4*64+h, bf);
    else if (nt == 1) v = ldf(bias, 2*64+h, bf) + ldf(bias, 5*64+h, bf);
    else              v = ldf(bias, 3*64+h, bf) + ldf(bias, 6*64+h, bf);
    bsum[idx] = v;
}

__global__ __launch_bounds__(256) void relu_kernel(
    const float* __restrict__ hn, const float* __restrict__ bsum,
    float* __restrict__ h)
{
    size_t idx = (size_t)blockIdx.x * 256 + threadIdx.x;
    if (idx >= (size_t)3 * N_NODES * HDIM) return;
    int nt = (int)(idx / ((size_t)N_NODES * HDIM));
    int hh = (int)(idx & 63);
    float v = hn[idx] + bsum[nt * 64 + hh];
    h[idx] = v > 0.f ? v : 0.f;
}

__global__ __launch_bounds__(256) void head_kernel(
    const float* __restrict__ h0, const void* __restrict__ Wout,
    const void* __restrict__ bout, const int* __restrict__ flag,
    void* __restrict__ out)
{
    __shared__ float sW[64 * 4];
    __shared__ float sb[4];
    int bf = flag[0];
    int tid = threadIdx.x;
    sW[tid] = ldf(Wout, tid, bf);
    if (tid < 4) sb[tid] = ldf(bout, tid, bf);
    __syncthreads();
    int i = blockIdx.x * 256 + tid;
    if (i >= N_NODES) return;
    float l0 = sb[0], l1 = sb[1], l2 = sb[2], l3 = sb[3];
    const float4* p = (const float4*)(h0 + (size_t)i * HDIM);
    #pragma unroll
    for (int k = 0; k < 16; ++k) {
        float4 a = p[k];
        int d = 4 * k;
        l0 += a.x * sW[d*4+0] + a.y * sW[(d+1)*4+0] + a.z * sW[(d+2)*4+0] + a.w * sW[(d+3)*4+0];
        l1 += a.x * sW[d*4+1] + a.y * sW[(d+1)*4+1] + a.z * sW[(d+2)*4+1] + a.w * sW[(d+3)*4+1];
        l2 += a.x * sW[d*4+2] + a.y * sW[(d+1)*4+2] + a.z * sW[(d+2)*4+2] + a.w * sW[(d+3)*4+2];
        l3 += a.x * sW[d*4+3] + a.y * sW[(d+1)*4+3] + a.z * sW[(d+2)*4+3] + a.w * sW[(d+3)*4+3];
    }
    float m = fmaxf(fmaxf(l0, l1), fmaxf(l2, l3));
    float e0 = __expf(l0 - m), e1 = __expf(l1 - m), e2 = __expf(l2 - m), e3 = __expf(l3 - m);
    float inv = 1.f / (e0 + e1 + e2 + e3);
    if (bf) {
        bf16* o = (bf16*)out;
        o[(size_t)4*i + 0] = __float2bfloat16(e0 * inv);
        o[(size_t)4*i + 1] = __float2bfloat16(e1 * inv);
        o[(size_t)4*i + 2] = __float2bfloat16(e2 * inv);
        o[(size_t)4*i + 3] = __float2bfloat16(e3 * inv);
    } else {
        float* o = (float*)out;
        o[(size_t)4*i + 0] = e0 * inv;
        o[(size_t)4*i + 1] = e1 * inv;
        o[(size_t)4*i + 2] = e2 * inv;
        o[(size_t)4*i + 3] = e3 * inv;
    }
}

struct P2 { const void* b; const void* f; };
static inline P2 off2(const void* base, size_t elem) {
    P2 r;
    r.b = (const void*)((const bf16*)base + elem);
    r.f = (const void*)((const float*)base + elem);
    return r;
}

extern "C" void kernel_launch(void* const* d_in, const int* in_sizes, int n_in,
                              void* d_out, int out_size, void* d_ws, size_t ws_size,
                              hipStream_t stream)
{
    const void* x     = d_in[0];
    const int*  edges = (const int*)d_in[1];
    const void* Wl0 = d_in[2];
    const void* Wr0 = d_in[3];
    const void* bl0 = d_in[4];
    const void* br0 = d_in[5];
    const void* att0 = d_in[6];
    const void* bias0 = d_in[7];
    const void* Wl1 = d_in[8];
    const void* Wr1 = d_in[9];
    const void* bl1 = d_in[10];
    const void* br1 = d_in[11];
    const void* att1 = d_in[12];
    const void* bias1 = d_in[13];
    const void* Wout = d_in[14];
    const void* bout = d_in[15];

    const int SRCt[7] = {0, 1, 1, 1, 2, 2, 2};
    const int DSTt[7] = {0, 0, 1, 2, 0, 1, 2};

    // ---- workspace layout ----
    float* h3  = (float*)d_ws;                                  // 3*N*H
    float* hn3 = h3 + (size_t)3 * N_NODES * HDIM;               // 3*N*H (38.4 MB)
    float* xl  = hn3 + (size_t)3 * N_NODES * HDIM;              // N*H
    float* xr  = xl + (size_t)N_NODES * HDIM;                   // N*H
    char* tail = (char*)(xr + (size_t)N_NODES * HDIM);

    size_t fixed = (size_t)tail - (size_t)d_ws;
    size_t need_full = fixed + ((size_t)NROWS + 1) * 4 + (size_t)7 * NEDGE * 4
                     + 2 * 256 * 4 + 192 * 4 + 4 + 2 * (size_t)N_NODES * 4 + 256;
    bool full = ws_size >= need_full;
    int NT = full ? 7 : 1;

    int* P        = (int*)tail;                                 // NT*N+1
    int* col_src  = P + ((size_t)NT * N_NODES + 1);             // NT*E
    int* bsums    = col_src + (size_t)NT * NEDGE;               // 256
    int* boffs    = bsums + 256;                                // 256
    float* bsum   = (float*)(boffs + 256);                      // 192
    int* flag     = (int*)(bsum + 192);                         // 1
    int* cnt;
    int* cursor;
    int* bcur = nullptr;
    unsigned* buf = nullptr;
    if (full) {
        // CSR build strictly precedes all hn3 use (stream-ordered) -> alias
        cnt    = (int*)hn3;                                     // NROWS (1.4 MB)
        cursor = cnt + NROWS;                                   // NROWS (1.4 MB)
        bcur   = cursor + NROWS;                                // NBUCK (87.5 KB)
        buf    = (unsigned*)(bcur + NBUCK + 64);                // 7E (22.4 MB) -> ~25.3 < 38.4 MB
    } else {
        cnt = flag + 1;                                         // N
        cursor = cnt + N_NODES;                                 // N
    }

    dim3 blk(256);
    int gLin  = (N_NODES + 15) / 16;                            // 3125
    int gRow  = (N_NODES + 3) / 4;
    int gRelu = (int)(((size_t)3 * N_NODES * HDIM + 255) / 256);
    int gHead = (N_NODES + 255) / 256;

    detect_kernel<<<1, 256, 0, stream>>>((const unsigned short*)x, flag);

    if (full) {
        int n = NROWS;
        int nb = (n + 2047) / 2048;                  // 171
        int gE7 = (7 * NEDGE + 255) / 256;
        hipMemsetAsync(cnt, 0, (size_t)n * sizeof(int), stream);
        hist_kernel<<<gE7, blk, 0, stream>>>(edges, cnt, 7);
        scanA_kernel<<<nb, blk, 0, stream>>>(cnt, bsums, n);
        scanB_kernel<<<1, blk, 0, stream>>>(bsums, boffs, nb, P, n);
        scanC_kernel<<<nb, blk, 0, stream>>>(cnt, boffs, P, cursor, n);
        bcur_init_kernel<<<(NBUCK + 255) / 256, blk, 0, stream>>>(P, bcur);
        pass1_kernel<<<gE7, blk, 0, stream>>>(edges, bcur, buf);
        pass2_kernel<<<NBUCK, blk, 0, stream>>>(buf, P, col_src);
    }

    for (int layer = 0; layer < 2; ++layer) {
        const void* Wl = layer ? Wl1 : Wl0;
        const void* Wr = layer ? Wr1 : Wr0;
        const void* bl = layer ? bl1 : bl0;
        const void* br = layer ? br1 : br0;
        const void* at = layer ? att1 : att0;
        const void* bi = layer ? bias1 : bias0;

        hipMemsetAsync(hn3, 0, (size_t)3 * N_NODES * HDIM * sizeof(float), stream);
        bsum_kernel<<<1, 192, 0, stream>>>(bi, flag, bsum);

        for (int t = 0; t < 7; ++t) {
            const int* rp;
            const int* cs;
            if (full) {
                rp = P + (size_t)t * N_NODES;
                cs = col_src;    // P holds GLOBAL positions into col_src
            } else {
                const int* et = edges + (size_t)t * 2 * NEDGE;
                int n = N_NODES;
                int nb = (n + 2047) / 2048;          // 25
                int gE1 = (NEDGE + 255) / 256;
                hipMemsetAsync(cnt, 0, (size_t)n * sizeof(int), stream);
                hist_kernel<<<gE1, blk, 0, stream>>>(et, cnt, 1);
                scanA_kernel<<<nb, blk, 0, stream>>>(cnt, bsums, n);
                scanB_kernel<<<1, blk, 0, stream>>>(bsums, boffs, nb, P, n);
                scanC_kernel<<<nb, blk, 0, stream>>>(cnt, boffs, P, cursor, n);
                scatter1_kernel<<<gE1, blk, 0, stream>>>(et, cursor, col_src);
                rp = P;
                cs = col_src;
            }

            if (layer == 0) {
                P2 fs = off2(x, (size_t)SRCt[t] * N_NODES * DIN);
                P2 fd = off2(x, (size_t)DSTt[t] * N_NODES * DIN);
                P2 wl = off2(Wl, (size_t)t * DIN * HDIM);
                P2 wr = off2(Wr, (size_t)t * DIN * HDIM);
                P2 bL = off2(bl, (size_t)t * HDIM);
                P2 bR = off2(br, (size_t)t * HDIM);
                lin_d32_kernel<<<dim3(gLin, 2), blk, 0, stream>>>(
                    fs.b, fs.f, fd.b, fd.f, wl.b, wl.f, wr.b, wr.f,
                    bL.b, bL.f, bR.b, bR.f, flag, xl, xr);
            } else {
                P2 wl = off2(Wl, (size_t)t * HDIM * HDIM);
                P2 wr = off2(Wr, (size_t)t * HDIM * HDIM);
                P2 bL = off2(bl, (size_t)t * HDIM);
                P2 bR = off2(br, (size_t)t * HDIM);
                lin_d64_kernel<<<dim3(gLin, 2), blk, 0, stream>>>(
                    h3 + (size_t)SRCt[t] * N_NODES * HDIM,
                    h3 + (size_t)DSTt[t] * N_NODES * HDIM,
                    wl.b, wl.f, wr.b, wr.f, bL.b, bL.f, bR.b, bR.f, flag, xl, xr);
            }

            P2 a2 = off2(at, (size_t)t * HDIM);
            gat_row_kernel<<<gRow, blk, 0, stream>>>(rp, cs, xl, xr,
                                                     a2.b, a2.f, flag,
                                                     hn3 + (size_t)DSTt[t] * N_NODES * HDIM);
        }
        relu_kernel<<<gRelu, blk, 0, stream>>>(hn3, bsum, h3);
    }

    head_kernel<<<gHead, blk, 0, stream>>>(h3, Wout, bout, flag, d_out);
}

// Round 7
// 2086.139 us; speedup vs baseline: 2.1774x; 1.4645x over previous
//
#include <hip/hip_runtime.h>
#include <hip/hip_bf16.h>

// HeteroGATv2: 3 node types x 50000 nodes, 7 edge types x 800000 edges,
// 2 GATv2 layers (H=64), softmax head (4 classes) on node type 0.
//
// R7: gat_row rewritten subgroup-parallel. Old version serialized a 6-step
// shfl reduce over each of ~16 edges per row (~640 dependent cycles). New:
// wave = 4 subgroups x 16 lanes; subgroup computes one edge's score via a
// 4-step 16-lane reduce (4 edges in flight), gathered xl rows stay in
// registers so the PV accumulation is shuffle-free FMAs, online softmax per
// 16-edge chunk. CSR build (R6 binned-16) and lin kernels unchanged.
//
// Dtype-adaptive (proven in R2): detector decides bf16 vs f32 once.

#define N_NODES 50000
#define NEDGE   800000
#define HDIM    64
#define DIN     32
#define NROWS   (7 * N_NODES)              // 350000 global rows (type-major)
#define BROWS   16                         // rows per bucket
#define NBUCK   (NROWS / BROWS)            // 21875 buckets (exact)

typedef __hip_bfloat16 bf16;

__device__ __forceinline__ float ldf(const void* p, size_t i, int bf) {
    return bf ? __bfloat162float(((const bf16*)p)[i]) : ((const float*)p)[i];
}

// flag[0] = 1 if x is bf16, 0 if f32.
__global__ void detect_kernel(const unsigned short* __restrict__ x, int* __restrict__ flag)
{
    __shared__ int sbad[256];
    int bad = 0;
    for (int i = threadIdx.x; i < 4096; i += 256) {
        unsigned short u = x[i];
        int ex = (u >> 7) & 0xff;
        bool zero = (u & 0x7fffu) == 0;
        if (!zero && (ex < 80 || ex > 140)) bad++;
    }
    sbad[threadIdx.x] = bad;
    __syncthreads();
    for (int s = 128; s > 0; s >>= 1) {
        if (threadIdx.x < s) sbad[threadIdx.x] += sbad[threadIdx.x + s];
        __syncthreads();
    }
    if (threadIdx.x == 0) flag[0] = (sbad[0] < 64) ? 1 : 0;
}

// ---------------- CSR build ----------------

__global__ __launch_bounds__(256) void hist_kernel(const int* __restrict__ edges,
                                                   int* __restrict__ cnt, int ntypes)
{
    int g = blockIdx.x * 256 + threadIdx.x;
    if (g >= ntypes * NEDGE) return;
    int t = g / NEDGE, i = g - t * NEDGE;
    int d = edges[(size_t)t * 2 * NEDGE + NEDGE + i];
    atomicAdd(&cnt[t * N_NODES + d], 1);
}

__global__ __launch_bounds__(256) void scanA_kernel(const int* __restrict__ cnt,
                                                    int* __restrict__ bsums, int n)
{
    __shared__ int lds[256];
    int tid = threadIdx.x;
    int base = blockIdx.x * 2048 + tid * 8;
    int s = 0;
    #pragma unroll
    for (int k = 0; k < 8; ++k) { int i = base + k; if (i < n) s += cnt[i]; }
    lds[tid] = s;
    __syncthreads();
    for (int o = 128; o > 0; o >>= 1) {
        if (tid < o) lds[tid] += lds[tid + o];
        __syncthreads();
    }
    if (tid == 0) bsums[blockIdx.x] = lds[0];
}

__global__ __launch_bounds__(256) void scanB_kernel(const int* __restrict__ bsums,
                                                    int* __restrict__ boffs, int nb,
                                                    int* __restrict__ P, int n)
{
    __shared__ int lds[256];
    int tid = threadIdx.x;
    int v = (tid < nb) ? bsums[tid] : 0;
    lds[tid] = v;
    __syncthreads();
    for (int off = 1; off < 256; off <<= 1) {
        int t2 = (tid >= off) ? lds[tid - off] : 0;
        __syncthreads();
        lds[tid] += t2;
        __syncthreads();
    }
    if (tid < nb) boffs[tid] = lds[tid] - v;
    if (tid == 255) P[n] = lds[255];
}

__global__ __launch_bounds__(256) void scanC_kernel(const int* __restrict__ cnt,
                                                    const int* __restrict__ boffs,
                                                    int* __restrict__ P,
                                                    int* __restrict__ cursor, int n)
{
    __shared__ int lds[256];
    int tid = threadIdx.x;
    int base = blockIdx.x * 2048 + tid * 8;
    int v[8];
    int s = 0;
    #pragma unroll
    for (int k = 0; k < 8; ++k) {
        int i = base + k;
        int c = (i < n) ? cnt[i] : 0;
        v[k] = s;
        s += c;
    }
    lds[tid] = s;
    __syncthreads();
    for (int off = 1; off < 256; off <<= 1) {
        int t2 = (tid >= off) ? lds[tid - off] : 0;
        __syncthreads();
        lds[tid] += t2;
        __syncthreads();
    }
    int off0 = boffs[blockIdx.x] + (lds[tid] - s);
    #pragma unroll
    for (int k = 0; k < 8; ++k) {
        int i = base + k;
        if (i < n) { int val = off0 + v[k]; P[i] = val; cursor[i] = val; }
    }
}

// bucket frontier init: bcur[b] = P[b*BROWS]
__global__ __launch_bounds__(256) void bcur_init_kernel(const int* __restrict__ P,
                                                        int* __restrict__ bcur)
{
    int b = blockIdx.x * 256 + threadIdx.x;
    if (b < NBUCK) bcur[b] = P[b * BROWS];
}

// pass 1: partition edges into 16-row buckets; payload = (r&15)<<16 | src
__global__ __launch_bounds__(256) void pass1_kernel(const int* __restrict__ edges,
                                                    int* __restrict__ bcur,
                                                    unsigned* __restrict__ buf)
{
    int g = blockIdx.x * 256 + threadIdx.x;
    if (g >= 7 * NEDGE) return;
    int t = g / NEDGE, i = g - t * NEDGE;
    int s = edges[(size_t)t * 2 * NEDGE + i];
    int d = edges[(size_t)t * 2 * NEDGE + NEDGE + i];
    int r = t * N_NODES + d;
    int pos = atomicAdd(&bcur[r >> 4], 1);
    buf[pos] = ((unsigned)(r & 15) << 16) | (unsigned)s;
}

// pass 2: one block per bucket; 16 fine row-cursors in LDS; dense region
__global__ __launch_bounds__(256) void pass2_kernel(const unsigned* __restrict__ buf,
                                                    const int* __restrict__ P,
                                                    int* __restrict__ col_src)
{
    __shared__ int scur[BROWS];
    int b = blockIdx.x;
    int r0 = b * BROWS;
    if (threadIdx.x < BROWS) scur[threadIdx.x] = P[r0 + threadIdx.x];
    __syncthreads();
    int start = P[r0];
    int end = P[r0 + BROWS];
    for (int i = start + threadIdx.x; i < end; i += 256) {
        unsigned v = buf[i];
        int ri = (int)(v >> 16);
        int s = (int)(v & 0xffffu);
        int pos = atomicAdd(&scur[ri], 1);
        col_src[pos] = s;
    }
}

// fallback direct scatter (single type)
__global__ __launch_bounds__(256) void scatter1_kernel(const int* __restrict__ et,
                                                       int* __restrict__ cursor,
                                                       int* __restrict__ col_src)
{
    int i = blockIdx.x * 256 + threadIdx.x;
    if (i >= NEDGE) return;
    int s = et[i], d = et[NEDGE + i];
    int pos = atomicAdd(&cursor[d], 1);
    col_src[pos] = s;
}

// ---------------- linear transforms (xl & xr in one dispatch) ----------------

__global__ __launch_bounds__(256) void lin_d32_kernel(
    const void* fLb, const void* fLf, const void* fRb, const void* fRf,
    const void* wLb, const void* wLf, const void* wRb, const void* wRf,
    const void* bLb, const void* bLf, const void* bRb, const void* bRf,
    const int* __restrict__ flag, float* __restrict__ xl, float* __restrict__ xr)
{
    __shared__ float sW[DIN * HDIM];
    __shared__ float sb[HDIM];
    int bf = flag[0];
    int side = blockIdx.y;
    const void* W    = side ? (bf ? wRb : wRf) : (bf ? wLb : wLf);
    const void* b    = side ? (bf ? bRb : bRf) : (bf ? bLb : bLf);
    const void* feat = side ? (bf ? fRb : fRf) : (bf ? fLb : fLf);
    float* out = side ? xr : xl;
    int tid = threadIdx.x;
    for (int k = tid; k < DIN * HDIM; k += 256) sW[k] = ldf(W, k, bf);
    if (tid < HDIM) sb[tid] = ldf(b, tid, bf);
    __syncthreads();
    int h = tid & 63;
    int slot = tid >> 6;
    int base = blockIdx.x * 16;
    for (int nn = slot; nn < 16; nn += 4) {
        int node = base + nn;
        if (node >= N_NODES) break;
        float acc = sb[h];
        #pragma unroll
        for (int d = 0; d < DIN; ++d)
            acc += ldf(feat, (size_t)node * DIN + d, bf) * sW[d * HDIM + h];
        out[(size_t)node * HDIM + h] = acc;
    }
}

__global__ __launch_bounds__(256) void lin_d64_kernel(
    const float* __restrict__ fL, const float* __restrict__ fR,
    const void* wLb, const void* wLf, const void* wRb, const void* wRf,
    const void* bLb, const void* bLf, const void* bRb, const void* bRf,
    const int* __restrict__ flag, float* __restrict__ xl, float* __restrict__ xr)
{
    __shared__ float sW[HDIM * HDIM];
    __shared__ float sb[HDIM];
    int bf = flag[0];
    int side = blockIdx.y;
    const void* W = side ? (bf ? wRb : wRf) : (bf ? wLb : wLf);
    const void* b = side ? (bf ? bRb : bRf) : (bf ? bLb : bLf);
    const float* feat = side ? fR : fL;
    float* out = side ? xr : xl;
    int tid = threadIdx.x;
    for (int k = tid; k < HDIM * HDIM; k += 256) sW[k] = ldf(W, k, bf);
    if (tid < HDIM) sb[tid] = ldf(b, tid, bf);
    __syncthreads();
    int h = tid & 63;
    int slot = tid >> 6;
    int base = blockIdx.x * 16;
    for (int nn = slot; nn < 16; nn += 4) {
        int node = base + nn;
        if (node >= N_NODES) break;
        float acc = sb[h];
        const float4* f4 = (const float4*)(feat + (size_t)node * HDIM);
        #pragma unroll
        for (int k = 0; k < 16; ++k) {
            float4 a = f4[k];
            acc += a.x * sW[(4*k+0) * HDIM + h] + a.y * sW[(4*k+1) * HDIM + h]
                 + a.z * sW[(4*k+2) * HDIM + h] + a.w * sW[(4*k+3) * HDIM + h];
        }
        out[(size_t)node * HDIM + h] = acc;
    }
}

// ---------------- fused GATv2 attention: subgroup-parallel ----------------
// Wave = 4 subgroups x 16 lanes; one wave per dst row. Subgroup g computes
// edge (chunk + it*4 + g)'s score via 4-step 16-lane shfl reduce; gathered
// xl float4s stay in registers for the shuffle-free PV accumulation.
// lane = (g<<4)|c: holds features 4c..4c+3.
__global__ __launch_bounds__(256) void gat_row_kernel(
    const int* __restrict__ rowptr, const int* __restrict__ col_src,
    const float* __restrict__ xl, const float* __restrict__ xr,
    const void* ab, const void* af, const int* __restrict__ flag,
    float* __restrict__ hn)
{
    int bf = flag[0];
    const void* att = bf ? ab : af;
    int wave = threadIdx.x >> 6;
    int lane = threadIdx.x & 63;
    int d = blockIdx.x * 4 + wave;
    if (d >= N_NODES) return;
    int rs = rowptr[d], re = rowptr[d + 1];
    if (re <= rs) return;

    int g = lane >> 4;        // subgroup 0..3
    int c = lane & 15;        // feature-quarter index

    float4 attv;
    attv.x = ldf(att, 4*c + 0, bf);
    attv.y = ldf(att, 4*c + 1, bf);
    attv.z = ldf(att, 4*c + 2, bf);
    attv.w = ldf(att, 4*c + 3, bf);
    float4 xrv = ((const float4*)(xr + (size_t)d * HDIM))[c];

    float4 acc = make_float4(0.f, 0.f, 0.f, 0.f);
    float m = -1e30f, s = 0.f;

    for (int cs0 = rs; cs0 < re; cs0 += 16) {
        float e[4];
        float4 xlv[4];
        #pragma unroll
        for (int it = 0; it < 4; ++it) {
            int ei = cs0 + it * 4 + g;
            bool valid = ei < re;
            float4 xv = make_float4(0.f, 0.f, 0.f, 0.f);
            if (valid) {
                int src = col_src[ei];
                xv = ((const float4*)(xl + (size_t)src * HDIM))[c];
            }
            xlv[it] = xv;
            float vx = xv.x + xrv.x; vx = vx > 0.f ? vx : 0.2f * vx;
            float vy = xv.y + xrv.y; vy = vy > 0.f ? vy : 0.2f * vy;
            float vz = xv.z + xrv.z; vz = vz > 0.f ? vz : 0.2f * vz;
            float vw = xv.w + xrv.w; vw = vw > 0.f ? vw : 0.2f * vw;
            float t = attv.x * vx + attv.y * vy + attv.z * vz + attv.w * vw;
            t += __shfl_xor(t, 1, 64);
            t += __shfl_xor(t, 2, 64);
            t += __shfl_xor(t, 4, 64);
            t += __shfl_xor(t, 8, 64);
            e[it] = valid ? t : -1e30f;   // uniform within subgroup
        }
        // chunk max over all 16 edges (4 per subgroup x 4 subgroups)
        float cm = fmaxf(fmaxf(e[0], e[1]), fmaxf(e[2], e[3]));
        cm = fmaxf(cm, __shfl_xor(cm, 16, 64));
        cm = fmaxf(cm, __shfl_xor(cm, 32, 64));
        if (cm > m) {
            float sc = __expf(m - cm);    // first chunk: exp(-inf) = 0, s/acc are 0
            s *= sc;
            acc.x *= sc; acc.y *= sc; acc.z *= sc; acc.w *= sc;
            m = cm;
        }
        #pragma unroll
        for (int it = 0; it < 4; ++it) {
            float w = __expf(e[it] - m);  // invalid: exp(-1e30 - m) = 0
            s += w;
            acc.x += w * xlv[it].x;
            acc.y += w * xlv[it].y;
            acc.z += w * xlv[it].z;
            acc.w += w * xlv[it].w;
        }
    }
    // reduce over subgroups (xor 16, 32): acc components and s
    acc.x += __shfl_xor(acc.x, 16, 64); acc.x += __shfl_xor(acc.x, 32, 64);
    acc.y += __shfl_xor(acc.y, 16, 64); acc.y += __shfl_xor(acc.y, 32, 64);
    acc.z += __shfl_xor(acc.z, 16, 64); acc.z += __shfl_xor(acc.z, 32, 64);
    acc.w += __shfl_xor(acc.w, 16, 64); acc.w += __shfl_xor(acc.w, 32, 64);
    s += __shfl_xor(s, 16, 64); s += __shfl_xor(s, 32, 64);

    if (g == 0) {
        float inv = 1.f / (s + 1e-16f);
        float4* op = (float4*)(hn + (size_t)d * HDIM);
        float4 old = op[c];
        op[c] = make_float4(old.x + acc.x * inv, old.y + acc.y * inv,
                            old.z + acc.z * inv, old.w + acc.w * inv);
    }
}

// ---------------- epilogue ----------------

__global__ void bsum_kernel(const void* __restrict__ bias, const int* __restrict__ flag,
                            float* __restrict__ bsum)
{
    int bf = flag[0];
    int idx = threadIdx.x;  // 192 = 3*64
    if (idx >= 192) return;
    int nt = idx >> 6, h = idx & 63;
    float v;
    if (nt == 0)      v = ldf(bias, 0*64+h, bf) + ldf(bias, 1*64+h, bf) + ldf(bias, 4*64+h, bf);
    else if (nt == 1) v = ldf(bias, 2*64+h, bf) + ldf(bias, 5*64+h, bf);
    else              v = ldf(bias, 3*64+h, bf) + ldf(bias, 6*64+h, bf);
    bsum[idx] = v;
}

__global__ __launch_bounds__(256) void relu_kernel(
    const float* __restrict__ hn, const float* __restrict__ bsum,
    float* __restrict__ h)
{
    size_t idx = (size_t)blockIdx.x * 256 + threadIdx.x;
    if (idx >= (size_t)3 * N_NODES * HDIM) return;
    int nt = (int)(idx / ((size_t)N_NODES * HDIM));
    int hh = (int)(idx & 63);
    float v = hn[idx] + bsum[nt * 64 + hh];
    h[idx] = v > 0.f ? v : 0.f;
}

__global__ __launch_bounds__(256) void head_kernel(
    const float* __restrict__ h0, const void* __restrict__ Wout,
    const void* __restrict__ bout, const int* __restrict__ flag,
    void* __restrict__ out)
{
    __shared__ float sW[64 * 4];
    __shared__ float sb[4];
    int bf = flag[0];
    int tid = threadIdx.x;
    sW[tid] = ldf(Wout, tid, bf);
    if (tid < 4) sb[tid] = ldf(bout, tid, bf);
    __syncthreads();
    int i = blockIdx.x * 256 + tid;
    if (i >= N_NODES) return;
    float l0 = sb[0], l1 = sb[1], l2 = sb[2], l3 = sb[3];
    const float4* p = (const float4*)(h0 + (size_t)i * HDIM);
    #pragma unroll
    for (int k = 0; k < 16; ++k) {
        float4 a = p[k];
        int d = 4 * k;
        l0 += a.x * sW[d*4+0] + a.y * sW[(d+1)*4+0] + a.z * sW[(d+2)*4+0] + a.w * sW[(d+3)*4+0];
        l1 += a.x * sW[d*4+1] + a.y * sW[(d+1)*4+1] + a.z * sW[(d+2)*4+1] + a.w * sW[(d+3)*4+1];
        l2 += a.x * sW[d*4+2] + a.y * sW[(d+1)*4+2] + a.z * sW[(d+2)*4+2] + a.w * sW[(d+3)*4+2];
        l3 += a.x * sW[d*4+3] + a.y * sW[(d+1)*4+3] + a.z * sW[(d+2)*4+3] + a.w * sW[(d+3)*4+3];
    }
    float m = fmaxf(fmaxf(l0, l1), fmaxf(l2, l3));
    float e0 = __expf(l0 - m), e1 = __expf(l1 - m), e2 = __expf(l2 - m), e3 = __expf(l3 - m);
    float inv = 1.f / (e0 + e1 + e2 + e3);
    if (bf) {
        bf16* o = (bf16*)out;
        o[(size_t)4*i + 0] = __float2bfloat16(e0 * inv);
        o[(size_t)4*i + 1] = __float2bfloat16(e1 * inv);
        o[(size_t)4*i + 2] = __float2bfloat16(e2 * inv);
        o[(size_t)4*i + 3] = __float2bfloat16(e3 * inv);
    } else {
        float* o = (float*)out;
        o[(size_t)4*i + 0] = e0 * inv;
        o[(size_t)4*i + 1] = e1 * inv;
        o[(size_t)4*i + 2] = e2 * inv;
        o[(size_t)4*i + 3] = e3 * inv;
    }
}

struct P2 { const void* b; const void* f; };
static inline P2 off2(const void* base, size_t elem) {
    P2 r;
    r.b = (const void*)((const bf16*)base + elem);
    r.f = (const void*)((const float*)base + elem);
    return r;
}

extern "C" void kernel_launch(void* const* d_in, const int* in_sizes, int n_in,
                              void* d_out, int out_size, void* d_ws, size_t ws_size,
                              hipStream_t stream)
{
    const void* x     = d_in[0];
    const int*  edges = (const int*)d_in[1];
    const void* Wl0 = d_in[2];
    const void* Wr0 = d_in[3];
    const void* bl0 = d_in[4];
    const void* br0 = d_in[5];
    const void* att0 = d_in[6];
    const void* bias0 = d_in[7];
    const void* Wl1 = d_in[8];
    const void* Wr1 = d_in[9];
    const void* bl1 = d_in[10];
    const void* br1 = d_in[11];
    const void* att1 = d_in[12];
    const void* bias1 = d_in[13];
    const void* Wout = d_in[14];
    const void* bout = d_in[15];

    const int SRCt[7] = {0, 1, 1, 1, 2, 2, 2};
    const int DSTt[7] = {0, 0, 1, 2, 0, 1, 2};

    // ---- workspace layout ----
    float* h3  = (float*)d_ws;                                  // 3*N*H
    float* hn3 = h3 + (size_t)3 * N_NODES * HDIM;               // 3*N*H (38.4 MB)
    float* xl  = hn3 + (size_t)3 * N_NODES * HDIM;              // N*H
    float* xr  = xl + (size_t)N_NODES * HDIM;                   // N*H
    char* tail = (char*)(xr + (size_t)N_NODES * HDIM);

    size_t fixed = (size_t)tail - (size_t)d_ws;
    size_t need_full = fixed + ((size_t)NROWS + 1) * 4 + (size_t)7 * NEDGE * 4
                     + 2 * 256 * 4 + 192 * 4 + 4 + 2 * (size_t)N_NODES * 4 + 256;
    bool full = ws_size >= need_full;
    int NT = full ? 7 : 1;

    int* P        = (int*)tail;                                 // NT*N+1
    int* col_src  = P + ((size_t)NT * N_NODES + 1);             // NT*E
    int* bsums    = col_src + (size_t)NT * NEDGE;               // 256
    int* boffs    = bsums + 256;                                // 256
    float* bsum   = (float*)(boffs + 256);                      // 192
    int* flag     = (int*)(bsum + 192);                         // 1
    int* cnt;
    int* cursor;
    int* bcur = nullptr;
    unsigned* buf = nullptr;
    if (full) {
        // CSR build strictly precedes all hn3 use (stream-ordered) -> alias
        cnt    = (int*)hn3;                                     // NROWS (1.4 MB)
        cursor = cnt + NROWS;                                   // NROWS (1.4 MB)
        bcur   = cursor + NROWS;                                // NBUCK (87.5 KB)
        buf    = (unsigned*)(bcur + NBUCK + 64);                // 7E (22.4 MB) -> ~25.3 < 38.4 MB
    } else {
        cnt = flag + 1;                                         // N
        cursor = cnt + N_NODES;                                 // N
    }

    dim3 blk(256);
    int gLin  = (N_NODES + 15) / 16;                            // 3125
    int gRow  = (N_NODES + 3) / 4;
    int gRelu = (int)(((size_t)3 * N_NODES * HDIM + 255) / 256);
    int gHead = (N_NODES + 255) / 256;

    detect_kernel<<<1, 256, 0, stream>>>((const unsigned short*)x, flag);

    if (full) {
        int n = NROWS;
        int nb = (n + 2047) / 2048;                  // 171
        int gE7 = (7 * NEDGE + 255) / 256;
        hipMemsetAsync(cnt, 0, (size_t)n * sizeof(int), stream);
        hist_kernel<<<gE7, blk, 0, stream>>>(edges, cnt, 7);
        scanA_kernel<<<nb, blk, 0, stream>>>(cnt, bsums, n);
        scanB_kernel<<<1, blk, 0, stream>>>(bsums, boffs, nb, P, n);
        scanC_kernel<<<nb, blk, 0, stream>>>(cnt, boffs, P, cursor, n);
        bcur_init_kernel<<<(NBUCK + 255) / 256, blk, 0, stream>>>(P, bcur);
        pass1_kernel<<<gE7, blk, 0, stream>>>(edges, bcur, buf);
        pass2_kernel<<<NBUCK, blk, 0, stream>>>(buf, P, col_src);
    }

    for (int layer = 0; layer < 2; ++layer) {
        const void* Wl = layer ? Wl1 : Wl0;
        const void* Wr = layer ? Wr1 : Wr0;
        const void* bl = layer ? bl1 : bl0;
        const void* br = layer ? br1 : br0;
        const void* at = layer ? att1 : att0;
        const void* bi = layer ? bias1 : bias0;

        hipMemsetAsync(hn3, 0, (size_t)3 * N_NODES * HDIM * sizeof(float), stream);
        bsum_kernel<<<1, 192, 0, stream>>>(bi, flag, bsum);

        for (int t = 0; t < 7; ++t) {
            const int* rp;
            const int* cs;
            if (full) {
                rp = P + (size_t)t * N_NODES;
                cs = col_src;    // P holds GLOBAL positions into col_src
            } else {
                const int* et = edges + (size_t)t * 2 * NEDGE;
                int n = N_NODES;
                int nb = (n + 2047) / 2048;          // 25
                int gE1 = (NEDGE + 255) / 256;
                hipMemsetAsync(cnt, 0, (size_t)n * sizeof(int), stream);
                hist_kernel<<<gE1, blk, 0, stream>>>(et, cnt, 1);
                scanA_kernel<<<nb, blk, 0, stream>>>(cnt, bsums, n);
                scanB_kernel<<<1, blk, 0, stream>>>(bsums, boffs, nb, P, n);
                scanC_kernel<<<nb, blk, 0, stream>>>(cnt, boffs, P, cursor, n);
                scatter1_kernel<<<gE1, blk, 0, stream>>>(et, cursor, col_src);
                rp = P;
                cs = col_src;
            }

            if (layer == 0) {
                P2 fs = off2(x, (size_t)SRCt[t] * N_NODES * DIN);
                P2 fd = off2(x, (size_t)DSTt[t] * N_NODES * DIN);
                P2 wl = off2(Wl, (size_t)t * DIN * HDIM);
                P2 wr = off2(Wr, (size_t)t * DIN * HDIM);
                P2 bL = off2(bl, (size_t)t * HDIM);
                P2 bR = off2(br, (size_t)t * HDIM);
                lin_d32_kernel<<<dim3(gLin, 2), blk, 0, stream>>>(
                    fs.b, fs.f, fd.b, fd.f, wl.b, wl.f, wr.b, wr.f,
                    bL.b, bL.f, bR.b, bR.f, flag, xl, xr);
            } else {
                P2 wl = off2(Wl, (size_t)t * HDIM * HDIM);
                P2 wr = off2(Wr, (size_t)t * HDIM * HDIM);
                P2 bL = off2(bl, (size_t)t * HDIM);
                P2 bR = off2(br, (size_t)t * HDIM);
                lin_d64_kernel<<<dim3(gLin, 2), blk, 0, stream>>>(
                    h3 + (size_t)SRCt[t] * N_NODES * HDIM,
                    h3 + (size_t)DSTt[t] * N_NODES * HDIM,
                    wl.b, wl.f, wr.b, wr.f, bL.b, bL.f, bR.b, bR.f, flag, xl, xr);
            }

            P2 a2 = off2(at, (size_t)t * HDIM);
            gat_row_kernel<<<gRow, blk, 0, stream>>>(rp, cs, xl, xr,
                                                     a2.b, a2.f, flag,
                                                     hn3 + (size_t)DSTt[t] * N_NODES * HDIM);
        }
        relu_kernel<<<gRelu, blk, 0, stream>>>(hn3, bsum, h3);
    }

    head_kernel<<<gHead, blk, 0, stream>>>(h3, Wout, bout, flag, d_out);
}

// Round 8
// 1493.096 us; speedup vs baseline: 3.0422x; 1.3972x over previous
//
#include <hip/hip_runtime.h>
#include <hip/hip_bf16.h>

// HeteroGATv2: 3 node types x 50000 nodes, 7 edge types x 800000 edges,
// 2 GATv2 layers (H=64), softmax head (4 classes) on node type 0.
//
// R8: deterministic radix-partition CSR build. Replaces hist(5.6M global
// atomics)+scan350K+atomic-frontier scatter with: k1 per-block LDS counts ->
// cnt2d[cb][blk]; k2 per-bucket block-prefix scan; k3 bucket-base scan;
// pass1 scatter at precomputed bases (LDS cursors only, contiguous runs ->
// full-line writes); pass2 per-bucket fine hist+scan in LDS writing P and
// col_src into a dense single-XCD region. Zero contended global atomics
// (R5 lesson: chained same-address atomics cost ~475ns each).
// Also: hn3 zero-init folded into gat_row (init flag on first edge type per
// dst-type) -- removes 2x38MB memsets.
//
// Dtype-adaptive (proven in R2): detector decides bf16 vs f32 once.

#define N_NODES 50000
#define NEDGE   800000
#define HDIM    64
#define DIN     32
#define NROWS   (7 * N_NODES)          // 350000 global rows (type-major)
#define CROWS   512                    // rows per coarse bucket
#define NCB     684                    // ceil(NROWS/CROWS)
#define TILE1   8192                   // edges per k1/pass1 block
#define NBLK1   684                    // ceil(7*NEDGE/TILE1)

typedef __hip_bfloat16 bf16;

__device__ __forceinline__ float ldf(const void* p, size_t i, int bf) {
    return bf ? __bfloat162float(((const bf16*)p)[i]) : ((const float*)p)[i];
}

// flag[0] = 1 if x is bf16, 0 if f32.
__global__ void detect_kernel(const unsigned short* __restrict__ x, int* __restrict__ flag)
{
    __shared__ int sbad[256];
    int bad = 0;
    for (int i = threadIdx.x; i < 4096; i += 256) {
        unsigned short u = x[i];
        int ex = (u >> 7) & 0xff;
        bool zero = (u & 0x7fffu) == 0;
        if (!zero && (ex < 80 || ex > 140)) bad++;
    }
    sbad[threadIdx.x] = bad;
    __syncthreads();
    for (int s = 128; s > 0; s >>= 1) {
        if (threadIdx.x < s) sbad[threadIdx.x] += sbad[threadIdx.x + s];
        __syncthreads();
    }
    if (threadIdx.x == 0) flag[0] = (sbad[0] < 64) ? 1 : 0;
}

// ---------------- radix-partition CSR build (full path) ----------------

// k1: per-block coarse-bucket counts -> cnt2d[cb*NBLK1 + blk]
__global__ __launch_bounds__(256) void k1_count_kernel(const int* __restrict__ edges,
                                                       int* __restrict__ cnt2d)
{
    __shared__ int lcount[NCB];
    for (int i = threadIdx.x; i < NCB; i += 256) lcount[i] = 0;
    __syncthreads();
    int g0 = blockIdx.x * TILE1;
    #pragma unroll 4
    for (int k = 0; k < TILE1 / 256; ++k) {
        int g = g0 + k * 256 + threadIdx.x;
        if (g < 7 * NEDGE) {
            int t = g / NEDGE, i = g - t * NEDGE;
            int d = edges[(size_t)t * 2 * NEDGE + NEDGE + i];
            int r = t * N_NODES + d;
            atomicAdd(&lcount[r >> 9], 1);
        }
    }
    __syncthreads();
    for (int i = threadIdx.x; i < NCB; i += 256)
        cnt2d[(size_t)i * NBLK1 + blockIdx.x] = lcount[i];
}

// k2: per coarse bucket, exclusive scan over blocks (in place); total -> cbase[cb]
__global__ __launch_bounds__(256) void k2_colscan_kernel(int* __restrict__ cnt2d,
                                                         int* __restrict__ cbase)
{
    __shared__ int sv[256];
    int t = threadIdx.x;
    int* col = cnt2d + (size_t)blockIdx.x * NBLK1;
    int a[3]; int s = 0;
    #pragma unroll
    for (int k = 0; k < 3; ++k) {
        int i = t * 3 + k;
        a[k] = (i < NBLK1) ? col[i] : 0;
        s += a[k];
    }
    sv[t] = s; __syncthreads();
    for (int off = 1; off < 256; off <<= 1) {
        int v = (t >= off) ? sv[t - off] : 0; __syncthreads();
        sv[t] += v; __syncthreads();
    }
    int excl = sv[t] - s;
    #pragma unroll
    for (int k = 0; k < 3; ++k) {
        int i = t * 3 + k;
        if (i < NBLK1) { col[i] = excl; excl += a[k]; }
    }
    if (t == 255) cbase[blockIdx.x] = sv[255];
}

// k3: exclusive scan of cbase[0..NCB) (in place); cbase[NCB]=P[NROWS]=total
__global__ __launch_bounds__(256) void k3_cscan_kernel(int* __restrict__ cbase,
                                                       int* __restrict__ P)
{
    __shared__ int sv[256];
    int t = threadIdx.x;
    int a[3]; int s = 0;
    #pragma unroll
    for (int k = 0; k < 3; ++k) {
        int i = t * 3 + k;
        a[k] = (i < NCB) ? cbase[i] : 0;
        s += a[k];
    }
    sv[t] = s; __syncthreads();
    for (int off = 1; off < 256; off <<= 1) {
        int v = (t >= off) ? sv[t - off] : 0; __syncthreads();
        sv[t] += v; __syncthreads();
    }
    int excl = sv[t] - s;
    #pragma unroll
    for (int k = 0; k < 3; ++k) {
        int i = t * 3 + k;
        if (i < NCB) { cbase[i] = excl; excl += a[k]; }
    }
    if (t == 255) { cbase[NCB] = sv[255]; P[NROWS] = sv[255]; }
}

// pass1: scatter edges to coarse buckets at precomputed bases (LDS cursors)
__global__ __launch_bounds__(256) void part1_kernel(const int* __restrict__ edges,
                                                    const int* __restrict__ cnt2d,
                                                    const int* __restrict__ cbase,
                                                    unsigned* __restrict__ buf)
{
    __shared__ int lcur[NCB];
    for (int i = threadIdx.x; i < NCB; i += 256)
        lcur[i] = cbase[i] + cnt2d[(size_t)i * NBLK1 + blockIdx.x];
    __syncthreads();
    int g0 = blockIdx.x * TILE1;
    #pragma unroll 4
    for (int k = 0; k < TILE1 / 256; ++k) {
        int g = g0 + k * 256 + threadIdx.x;
        if (g < 7 * NEDGE) {
            int t = g / NEDGE, i = g - t * NEDGE;
            int s = edges[(size_t)t * 2 * NEDGE + i];
            int d = edges[(size_t)t * 2 * NEDGE + NEDGE + i];
            int r = t * N_NODES + d;
            int pos = atomicAdd(&lcur[r >> 9], 1);
            buf[pos] = ((unsigned)(r & 511) << 16) | (unsigned)s;
        }
    }
}

// pass2: one block per coarse bucket; fine hist+scan in LDS -> P + col_src
__global__ __launch_bounds__(256) void part2_kernel(const unsigned* __restrict__ buf,
                                                    const int* __restrict__ cbase,
                                                    int* __restrict__ P,
                                                    int* __restrict__ col_src)
{
    __shared__ int fcnt[CROWS];
    __shared__ int fpos[CROWS];
    __shared__ int sv[256];
    int b = blockIdx.x;
    int t = threadIdx.x;
    int start = cbase[b], end = cbase[b + 1];
    fcnt[2 * t] = 0; fcnt[2 * t + 1] = 0;
    __syncthreads();
    for (int i = start + t; i < end; i += 256)
        atomicAdd(&fcnt[buf[i] >> 16], 1);
    __syncthreads();
    int a0 = fcnt[2 * t], a1 = fcnt[2 * t + 1];
    int s = a0 + a1;
    sv[t] = s; __syncthreads();
    for (int off = 1; off < 256; off <<= 1) {
        int v = (t >= off) ? sv[t - off] : 0; __syncthreads();
        sv[t] += v; __syncthreads();
    }
    int excl = sv[t] - s;
    fpos[2 * t] = excl; fpos[2 * t + 1] = excl + a0;
    int r0 = b * CROWS;
    int rows_in = NROWS - r0; if (rows_in > CROWS) rows_in = CROWS;
    if (2 * t < rows_in)     P[r0 + 2 * t]     = start + excl;
    if (2 * t + 1 < rows_in) P[r0 + 2 * t + 1] = start + excl + a0;
    __syncthreads();
    for (int i = start + t; i < end; i += 256) {
        unsigned v = buf[i];
        int pos = start + atomicAdd(&fpos[v >> 16], 1);
        col_src[pos] = (int)(v & 0xffffu);
    }
}

// ---------------- fallback CSR build (ws-limited): per (layer,type) ----------------

__global__ __launch_bounds__(256) void hist_kernel(const int* __restrict__ edges,
                                                   int* __restrict__ cnt, int ntypes)
{
    int g = blockIdx.x * 256 + threadIdx.x;
    if (g >= ntypes * NEDGE) return;
    int t = g / NEDGE, i = g - t * NEDGE;
    int d = edges[(size_t)t * 2 * NEDGE + NEDGE + i];
    atomicAdd(&cnt[t * N_NODES + d], 1);
}

__global__ __launch_bounds__(256) void scanA_kernel(const int* __restrict__ cnt,
                                                    int* __restrict__ bsums, int n)
{
    __shared__ int lds[256];
    int tid = threadIdx.x;
    int base = blockIdx.x * 2048 + tid * 8;
    int s = 0;
    #pragma unroll
    for (int k = 0; k < 8; ++k) { int i = base + k; if (i < n) s += cnt[i]; }
    lds[tid] = s;
    __syncthreads();
    for (int o = 128; o > 0; o >>= 1) {
        if (tid < o) lds[tid] += lds[tid + o];
        __syncthreads();
    }
    if (tid == 0) bsums[blockIdx.x] = lds[0];
}

__global__ __launch_bounds__(256) void scanB_kernel(const int* __restrict__ bsums,
                                                    int* __restrict__ boffs, int nb,
                                                    int* __restrict__ P, int n)
{
    __shared__ int lds[256];
    int tid = threadIdx.x;
    int v = (tid < nb) ? bsums[tid] : 0;
    lds[tid] = v;
    __syncthreads();
    for (int off = 1; off < 256; off <<= 1) {
        int t2 = (tid >= off) ? lds[tid - off] : 0;
        __syncthreads();
        lds[tid] += t2;
        __syncthreads();
    }
    if (tid < nb) boffs[tid] = lds[tid] - v;
    if (tid == 255) P[n] = lds[255];
}

__global__ __launch_bounds__(256) void scanC_kernel(const int* __restrict__ cnt,
                                                    const int* __restrict__ boffs,
                                                    int* __restrict__ P,
                                                    int* __restrict__ cursor, int n)
{
    __shared__ int lds[256];
    int tid = threadIdx.x;
    int base = blockIdx.x * 2048 + tid * 8;
    int v[8];
    int s = 0;
    #pragma unroll
    for (int k = 0; k < 8; ++k) {
        int i = base + k;
        int c = (i < n) ? cnt[i] : 0;
        v[k] = s;
        s += c;
    }
    lds[tid] = s;
    __syncthreads();
    for (int off = 1; off < 256; off <<= 1) {
        int t2 = (tid >= off) ? lds[tid - off] : 0;
        __syncthreads();
        lds[tid] += t2;
        __syncthreads();
    }
    int off0 = boffs[blockIdx.x] + (lds[tid] - s);
    #pragma unroll
    for (int k = 0; k < 8; ++k) {
        int i = base + k;
        if (i < n) { int val = off0 + v[k]; P[i] = val; cursor[i] = val; }
    }
}

__global__ __launch_bounds__(256) void scatter1_kernel(const int* __restrict__ et,
                                                       int* __restrict__ cursor,
                                                       int* __restrict__ col_src)
{
    int i = blockIdx.x * 256 + threadIdx.x;
    if (i >= NEDGE) return;
    int s = et[i], d = et[NEDGE + i];
    int pos = atomicAdd(&cursor[d], 1);
    col_src[pos] = s;
}

// ---------------- linear transforms (xl & xr in one dispatch) ----------------

__global__ __launch_bounds__(256) void lin_d32_kernel(
    const void* fLb, const void* fLf, const void* fRb, const void* fRf,
    const void* wLb, const void* wLf, const void* wRb, const void* wRf,
    const void* bLb, const void* bLf, const void* bRb, const void* bRf,
    const int* __restrict__ flag, float* __restrict__ xl, float* __restrict__ xr)
{
    __shared__ float sW[DIN * HDIM];
    __shared__ float sb[HDIM];
    int bf = flag[0];
    int side = blockIdx.y;
    const void* W    = side ? (bf ? wRb : wRf) : (bf ? wLb : wLf);
    const void* b    = side ? (bf ? bRb : bRf) : (bf ? bLb : bLf);
    const void* feat = side ? (bf ? fRb : fRf) : (bf ? fLb : fLf);
    float* out = side ? xr : xl;
    int tid = threadIdx.x;
    for (int k = tid; k < DIN * HDIM; k += 256) sW[k] = ldf(W, k, bf);
    if (tid < HDIM) sb[tid] = ldf(b, tid, bf);
    __syncthreads();
    int h = tid & 63;
    int slot = tid >> 6;
    int base = blockIdx.x * 16;
    for (int nn = slot; nn < 16; nn += 4) {
        int node = base + nn;
        if (node >= N_NODES) break;
        float acc = sb[h];
        #pragma unroll
        for (int d = 0; d < DIN; ++d)
            acc += ldf(feat, (size_t)node * DIN + d, bf) * sW[d * HDIM + h];
        out[(size_t)node * HDIM + h] = acc;
    }
}

__global__ __launch_bounds__(256) void lin_d64_kernel(
    const float* __restrict__ fL, const float* __restrict__ fR,
    const void* wLb, const void* wLf, const void* wRb, const void* wRf,
    const void* bLb, const void* bLf, const void* bRb, const void* bRf,
    const int* __restrict__ flag, float* __restrict__ xl, float* __restrict__ xr)
{
    __shared__ float sW[HDIM * HDIM];
    __shared__ float sb[HDIM];
    int bf = flag[0];
    int side = blockIdx.y;
    const void* W = side ? (bf ? wRb : wRf) : (bf ? wLb : wLf);
    const void* b = side ? (bf ? bRb : bRf) : (bf ? bLb : bLf);
    const float* feat = side ? fR : fL;
    float* out = side ? xr : xl;
    int tid = threadIdx.x;
    for (int k = tid; k < HDIM * HDIM; k += 256) sW[k] = ldf(W, k, bf);
    if (tid < HDIM) sb[tid] = ldf(b, tid, bf);
    __syncthreads();
    int h = tid & 63;
    int slot = tid >> 6;
    int base = blockIdx.x * 16;
    for (int nn = slot; nn < 16; nn += 4) {
        int node = base + nn;
        if (node >= N_NODES) break;
        float acc = sb[h];
        const float4* f4 = (const float4*)(feat + (size_t)node * HDIM);
        #pragma unroll
        for (int k = 0; k < 16; ++k) {
            float4 a = f4[k];
            acc += a.x * sW[(4*k+0) * HDIM + h] + a.y * sW[(4*k+1) * HDIM + h]
                 + a.z * sW[(4*k+2) * HDIM + h] + a.w * sW[(4*k+3) * HDIM + h];
        }
        out[(size_t)node * HDIM + h] = acc;
    }
}

// ---------------- fused GATv2 attention: subgroup-parallel ----------------
// init=1: overwrite hn (first edge type for this dst type), else accumulate.
__global__ __launch_bounds__(256) void gat_row_kernel(
    const int* __restrict__ rowptr, const int* __restrict__ col_src,
    const float* __restrict__ xl, const float* __restrict__ xr,
    const void* ab, const void* af, const int* __restrict__ flag,
    float* __restrict__ hn, int init)
{
    int bf = flag[0];
    const void* att = bf ? ab : af;
    int wave = threadIdx.x >> 6;
    int lane = threadIdx.x & 63;
    int d = blockIdx.x * 4 + wave;
    if (d >= N_NODES) return;
    int rs = rowptr[d], re = rowptr[d + 1];

    int g = lane >> 4;        // subgroup 0..3
    int c = lane & 15;        // feature-quarter index

    if (re <= rs) {
        if (init && g == 0)
            ((float4*)(hn + (size_t)d * HDIM))[c] = make_float4(0.f, 0.f, 0.f, 0.f);
        return;
    }

    float4 attv;
    attv.x = ldf(att, 4*c + 0, bf);
    attv.y = ldf(att, 4*c + 1, bf);
    attv.z = ldf(att, 4*c + 2, bf);
    attv.w = ldf(att, 4*c + 3, bf);
    float4 xrv = ((const float4*)(xr + (size_t)d * HDIM))[c];

    float4 acc = make_float4(0.f, 0.f, 0.f, 0.f);
    float m = -1e30f, s = 0.f;

    for (int cs0 = rs; cs0 < re; cs0 += 16) {
        float e[4];
        float4 xlv[4];
        #pragma unroll
        for (int it = 0; it < 4; ++it) {
            int ei = cs0 + it * 4 + g;
            bool valid = ei < re;
            float4 xv = make_float4(0.f, 0.f, 0.f, 0.f);
            if (valid) {
                int src = col_src[ei];
                xv = ((const float4*)(xl + (size_t)src * HDIM))[c];
            }
            xlv[it] = xv;
            float vx = xv.x + xrv.x; vx = vx > 0.f ? vx : 0.2f * vx;
            float vy = xv.y + xrv.y; vy = vy > 0.f ? vy : 0.2f * vy;
            float vz = xv.z + xrv.z; vz = vz > 0.f ? vz : 0.2f * vz;
            float vw = xv.w + xrv.w; vw = vw > 0.f ? vw : 0.2f * vw;
            float t = attv.x * vx + attv.y * vy + attv.z * vz + attv.w * vw;
            t += __shfl_xor(t, 1, 64);
            t += __shfl_xor(t, 2, 64);
            t += __shfl_xor(t, 4, 64);
            t += __shfl_xor(t, 8, 64);
            e[it] = valid ? t : -1e30f;
        }
        float cm = fmaxf(fmaxf(e[0], e[1]), fmaxf(e[2], e[3]));
        cm = fmaxf(cm, __shfl_xor(cm, 16, 64));
        cm = fmaxf(cm, __shfl_xor(cm, 32, 64));
        if (cm > m) {
            float sc = __expf(m - cm);
            s *= sc;
            acc.x *= sc; acc.y *= sc; acc.z *= sc; acc.w *= sc;
            m = cm;
        }
        #pragma unroll
        for (int it = 0; it < 4; ++it) {
            float w = __expf(e[it] - m);
            s += w;
            acc.x += w * xlv[it].x;
            acc.y += w * xlv[it].y;
            acc.z += w * xlv[it].z;
            acc.w += w * xlv[it].w;
        }
    }
    acc.x += __shfl_xor(acc.x, 16, 64); acc.x += __shfl_xor(acc.x, 32, 64);
    acc.y += __shfl_xor(acc.y, 16, 64); acc.y += __shfl_xor(acc.y, 32, 64);
    acc.z += __shfl_xor(acc.z, 16, 64); acc.z += __shfl_xor(acc.z, 32, 64);
    acc.w += __shfl_xor(acc.w, 16, 64); acc.w += __shfl_xor(acc.w, 32, 64);
    s += __shfl_xor(s, 16, 64); s += __shfl_xor(s, 32, 64);

    if (g == 0) {
        float inv = 1.f / (s + 1e-16f);
        float4* op = (float4*)(hn + (size_t)d * HDIM);
        if (init) {
            op[c] = make_float4(acc.x * inv, acc.y * inv, acc.z * inv, acc.w * inv);
        } else {
            float4 old = op[c];
            op[c] = make_float4(old.x + acc.x * inv, old.y + acc.y * inv,
                                old.z + acc.z * inv, old.w + acc.w * inv);
        }
    }
}

// ---------------- epilogue ----------------

__global__ void bsum_kernel(const void* __restrict__ bias, const int* __restrict__ flag,
                            float* __restrict__ bsum)
{
    int bf = flag[0];
    int idx = threadIdx.x;  // 192 = 3*64
    if (idx >= 192) return;
    int nt = idx >> 6, h = idx & 63;
    float v;
    if (nt == 0)      v = ldf(bias, 0*64+h, bf) + ldf(bias, 1*64+h, bf) + ldf(bias, 4*64+h, bf);
    else if (nt == 1) v = ldf(bias, 2*64+h, bf) + ldf(bias, 5*64+h, bf);
    else              v = ldf(bias, 3*64+h, bf) + ldf(bias, 6*64+h, bf);
    bsum[idx] = v;
}

__global__ __launch_bounds__(256) void relu_kernel(
    const float* __restrict__ hn, const float* __restrict__ bsum,
    float* __restrict__ h)
{
    size_t idx = (size_t)blockIdx.x * 256 + threadIdx.x;
    if (idx >= (size_t)3 * N_NODES * HDIM) return;
    int nt = (int)(idx / ((size_t)N_NODES * HDIM));
    int hh = (int)(idx & 63);
    float v = hn[idx] + bsum[nt * 64 + hh];
    h[idx] = v > 0.f ? v : 0.f;
}

__global__ __launch_bounds__(256) void head_kernel(
    const float* __restrict__ h0, const void* __restrict__ Wout,
    const void* __restrict__ bout, const int* __restrict__ flag,
    void* __restrict__ out)
{
    __shared__ float sW[64 * 4];
    __shared__ float sb[4];
    int bf = flag[0];
    int tid = threadIdx.x;
    sW[tid] = ldf(Wout, tid, bf);
    if (tid < 4) sb[tid] = ldf(bout, tid, bf);
    __syncthreads();
    int i = blockIdx.x * 256 + tid;
    if (i >= N_NODES) return;
    float l0 = sb[0], l1 = sb[1], l2 = sb[2], l3 = sb[3];
    const float4* p = (const float4*)(h0 + (size_t)i * HDIM);
    #pragma unroll
    for (int k = 0; k < 16; ++k) {
        float4 a = p[k];
        int d = 4 * k;
        l0 += a.x * sW[d*4+0] + a.y * sW[(d+1)*4+0] + a.z * sW[(d+2)*4+0] + a.w * sW[(d+3)*4+0];
        l1 += a.x * sW[d*4+1] + a.y * sW[(d+1)*4+1] + a.z * sW[(d+2)*4+1] + a.w * sW[(d+3)*4+1];
        l2 += a.x * sW[d*4+2] + a.y * sW[(d+1)*4+2] + a.z * sW[(d+2)*4+2] + a.w * sW[(d+3)*4+2];
        l3 += a.x * sW[d*4+3] + a.y * sW[(d+1)*4+3] + a.z * sW[(d+2)*4+3] + a.w * sW[(d+3)*4+3];
    }
    float m = fmaxf(fmaxf(l0, l1), fmaxf(l2, l3));
    float e0 = __expf(l0 - m), e1 = __expf(l1 - m), e2 = __expf(l2 - m), e3 = __expf(l3 - m);
    float inv = 1.f / (e0 + e1 + e2 + e3);
    if (bf) {
        bf16* o = (bf16*)out;
        o[(size_t)4*i + 0] = __float2bfloat16(e0 * inv);
        o[(size_t)4*i + 1] = __float2bfloat16(e1 * inv);
        o[(size_t)4*i + 2] = __float2bfloat16(e2 * inv);
        o[(size_t)4*i + 3] = __float2bfloat16(e3 * inv);
    } else {
        float* o = (float*)out;
        o[(size_t)4*i + 0] = e0 * inv;
        o[(size_t)4*i + 1] = e1 * inv;
        o[(size_t)4*i + 2] = e2 * inv;
        o[(size_t)4*i + 3] = e3 * inv;
    }
}

struct P2 { const void* b; const void* f; };
static inline P2 off2(const void* base, size_t elem) {
    P2 r;
    r.b = (const void*)((const bf16*)base + elem);
    r.f = (const void*)((const float*)base + elem);
    return r;
}

extern "C" void kernel_launch(void* const* d_in, const int* in_sizes, int n_in,
                              void* d_out, int out_size, void* d_ws, size_t ws_size,
                              hipStream_t stream)
{
    const void* x     = d_in[0];
    const int*  edges = (const int*)d_in[1];
    const void* Wl0 = d_in[2];
    const void* Wr0 = d_in[3];
    const void* bl0 = d_in[4];
    const void* br0 = d_in[5];
    const void* att0 = d_in[6];
    const void* bias0 = d_in[7];
    const void* Wl1 = d_in[8];
    const void* Wr1 = d_in[9];
    const void* bl1 = d_in[10];
    const void* br1 = d_in[11];
    const void* att1 = d_in[12];
    const void* bias1 = d_in[13];
    const void* Wout = d_in[14];
    const void* bout = d_in[15];

    const int SRCt[7] = {0, 1, 1, 1, 2, 2, 2};
    const int DSTt[7] = {0, 0, 1, 2, 0, 1, 2};

    // ---- workspace layout ----
    float* h3  = (float*)d_ws;                                  // 3*N*H
    float* hn3 = h3 + (size_t)3 * N_NODES * HDIM;               // 3*N*H (38.4 MB)
    float* xl  = hn3 + (size_t)3 * N_NODES * HDIM;              // N*H
    float* xr  = xl + (size_t)N_NODES * HDIM;                   // N*H
    char* tail = (char*)(xr + (size_t)N_NODES * HDIM);

    size_t fixed = (size_t)tail - (size_t)d_ws;
    size_t need_full = fixed + ((size_t)NROWS + 1) * 4 + (size_t)7 * NEDGE * 4
                     + (NCB + 1) * 4 + 2 * 256 * 4 + 192 * 4 + 4
                     + 2 * (size_t)N_NODES * 4 + 256;
    bool full = ws_size >= need_full;
    int NT = full ? 7 : 1;

    int* P        = (int*)tail;                                 // NT*N+1
    int* col_src  = P + ((size_t)NT * N_NODES + 1);             // NT*E
    int* cbase    = col_src + (size_t)NT * NEDGE;               // NCB+1
    int* bsums    = cbase + (NCB + 1);                          // 256
    int* boffs    = bsums + 256;                                // 256
    float* bsum   = (float*)(boffs + 256);                      // 192
    int* flag     = (int*)(bsum + 192);                         // 1
    int* cnt      = flag + 1;                                   // N (fallback)
    int* cursor   = cnt + N_NODES;                              // N (fallback)

    // full path: buf + cnt2d alias into hn3 (CSR build precedes first gat_row,
    // which zero-inits hn3 via init flag -- stream-ordered, no memset needed)
    unsigned* buf = (unsigned*)hn3;                             // 7E (22.4 MB)
    int* cnt2d    = (int*)(buf + (size_t)7 * NEDGE);            // NCB*NBLK1 (1.87 MB)

    dim3 blk(256);
    int gLin  = (N_NODES + 15) / 16;                            // 3125
    int gRow  = (N_NODES + 3) / 4;
    int gRelu = (int)(((size_t)3 * N_NODES * HDIM + 255) / 256);
    int gHead = (N_NODES + 255) / 256;

    detect_kernel<<<1, 256, 0, stream>>>((const unsigned short*)x, flag);

    if (full) {
        k1_count_kernel<<<NBLK1, blk, 0, stream>>>(edges, cnt2d);
        k2_colscan_kernel<<<NCB, blk, 0, stream>>>(cnt2d, cbase);
        k3_cscan_kernel<<<1, blk, 0, stream>>>(cbase, P);
        part1_kernel<<<NBLK1, blk, 0, stream>>>(edges, cnt2d, cbase, buf);
        part2_kernel<<<NCB, blk, 0, stream>>>(buf, cbase, P, col_src);
    }

    for (int layer = 0; layer < 2; ++layer) {
        const void* Wl = layer ? Wl1 : Wl0;
        const void* Wr = layer ? Wr1 : Wr0;
        const void* bl = layer ? bl1 : bl0;
        const void* br = layer ? br1 : br0;
        const void* at = layer ? att1 : att0;
        const void* bi = layer ? bias1 : bias0;

        bsum_kernel<<<1, 192, 0, stream>>>(bi, flag, bsum);

        for (int t = 0; t < 7; ++t) {
            const int* rp;
            const int* cs;
            if (full) {
                rp = P + (size_t)t * N_NODES;
                cs = col_src;    // P holds GLOBAL positions into col_src
            } else {
                const int* et = edges + (size_t)t * 2 * NEDGE;
                int n = N_NODES;
                int nb = (n + 2047) / 2048;          // 25
                int gE1 = (NEDGE + 255) / 256;
                hipMemsetAsync(cnt, 0, (size_t)n * sizeof(int), stream);
                hist_kernel<<<gE1, blk, 0, stream>>>(et, cnt, 1);
                scanA_kernel<<<nb, blk, 0, stream>>>(cnt, bsums, n);
                scanB_kernel<<<1, blk, 0, stream>>>(bsums, boffs, nb, P, n);
                scanC_kernel<<<nb, blk, 0, stream>>>(cnt, boffs, P, cursor, n);
                scatter1_kernel<<<gE1, blk, 0, stream>>>(et, cursor, col_src);
                rp = P;
                cs = col_src;
            }

            if (layer == 0) {
                P2 fs = off2(x, (size_t)SRCt[t] * N_NODES * DIN);
                P2 fd = off2(x, (size_t)DSTt[t] * N_NODES * DIN);
                P2 wl = off2(Wl, (size_t)t * DIN * HDIM);
                P2 wr = off2(Wr, (size_t)t * DIN * HDIM);
                P2 bL = off2(bl, (size_t)t * HDIM);
                P2 bR = off2(br, (size_t)t * HDIM);
                lin_d32_kernel<<<dim3(gLin, 2), blk, 0, stream>>>(
                    fs.b, fs.f, fd.b, fd.f, wl.b, wl.f, wr.b, wr.f,
                    bL.b, bL.f, bR.b, bR.f, flag, xl, xr);
            } else {
                P2 wl = off2(Wl, (size_t)t * HDIM * HDIM);
                P2 wr = off2(Wr, (size_t)t * HDIM * HDIM);
                P2 bL = off2(bl, (size_t)t * HDIM);
                P2 bR = off2(br, (size_t)t * HDIM);
                lin_d64_kernel<<<dim3(gLin, 2), blk, 0, stream>>>(
                    h3 + (size_t)SRCt[t] * N_NODES * HDIM,
                    h3 + (size_t)DSTt[t] * N_NODES * HDIM,
                    wl.b, wl.f, wr.b, wr.f, bL.b, bL.f, bR.b, bR.f, flag, xl, xr);
            }

            // first edge type per dst-type overwrites (zero-init fold): t=0,2,3
            int init = (t == 0 || t == 2 || t == 3) ? 1 : 0;
            P2 a2 = off2(at, (size_t)t * HDIM);
            gat_row_kernel<<<gRow, blk, 0, stream>>>(rp, cs, xl, xr,
                                                     a2.b, a2.f, flag,
                                                     hn3 + (size_t)DSTt[t] * N_NODES * HDIM,
                                                     init);
        }
        relu_kernel<<<gRelu, blk, 0, stream>>>(hn3, bsum, h3);
    }

    head_kernel<<<gHead, blk, 0, stream>>>(h3, Wout, bout, flag, d_out);
}

// Round 9
// 1451.299 us; speedup vs baseline: 3.1299x; 1.0288x over previous
//
#include <hip/hip_runtime.h>
#include <hip/hip_bf16.h>

// HeteroGATv2: 3 node types x 50000 nodes, 7 edge types x 800000 edges,
// 2 GATv2 layers (H=64), softmax head (4 classes) on node type 0.
//
// R9: lin kernels rewritten weight-in-registers. R8 profile showed lin_d64
// at 68us, 7% HBM, VALUBusy 36%, bottlenecked on ds_read_b32 issue throughput
// (every FMA sourced sW from LDS: 256 reads/thread @ ~6cyc). Each thread
// computes one output column h -> needs exactly W[:,h] = 64 floats = 64 VGPRs,
// filled once via coalesced L2-resident global loads; inner loop is pure
// reg-FMA + broadcast feat float4. 32 nodes/block amortizes the fill.
// CSR build (R8 radix), gat_row (R7 subgroup), epilogue unchanged.
//
// Dtype-adaptive (proven in R2): detector decides bf16 vs f32 once.

#define N_NODES 50000
#define NEDGE   800000
#define HDIM    64
#define DIN     32
#define NROWS   (7 * N_NODES)          // 350000 global rows (type-major)
#define CROWS   512                    // rows per coarse bucket
#define NCB     684                    // ceil(NROWS/CROWS)
#define TILE1   8192                   // edges per k1/pass1 block
#define NBLK1   684                    // ceil(7*NEDGE/TILE1)

typedef __hip_bfloat16 bf16;

__device__ __forceinline__ float ldf(const void* p, size_t i, int bf) {
    return bf ? __bfloat162float(((const bf16*)p)[i]) : ((const float*)p)[i];
}

// flag[0] = 1 if x is bf16, 0 if f32.
__global__ void detect_kernel(const unsigned short* __restrict__ x, int* __restrict__ flag)
{
    __shared__ int sbad[256];
    int bad = 0;
    for (int i = threadIdx.x; i < 4096; i += 256) {
        unsigned short u = x[i];
        int ex = (u >> 7) & 0xff;
        bool zero = (u & 0x7fffu) == 0;
        if (!zero && (ex < 80 || ex > 140)) bad++;
    }
    sbad[threadIdx.x] = bad;
    __syncthreads();
    for (int s = 128; s > 0; s >>= 1) {
        if (threadIdx.x < s) sbad[threadIdx.x] += sbad[threadIdx.x + s];
        __syncthreads();
    }
    if (threadIdx.x == 0) flag[0] = (sbad[0] < 64) ? 1 : 0;
}

// ---------------- radix-partition CSR build (full path) ----------------

__global__ __launch_bounds__(256) void k1_count_kernel(const int* __restrict__ edges,
                                                       int* __restrict__ cnt2d)
{
    __shared__ int lcount[NCB];
    for (int i = threadIdx.x; i < NCB; i += 256) lcount[i] = 0;
    __syncthreads();
    int g0 = blockIdx.x * TILE1;
    #pragma unroll 4
    for (int k = 0; k < TILE1 / 256; ++k) {
        int g = g0 + k * 256 + threadIdx.x;
        if (g < 7 * NEDGE) {
            int t = g / NEDGE, i = g - t * NEDGE;
            int d = edges[(size_t)t * 2 * NEDGE + NEDGE + i];
            int r = t * N_NODES + d;
            atomicAdd(&lcount[r >> 9], 1);
        }
    }
    __syncthreads();
    for (int i = threadIdx.x; i < NCB; i += 256)
        cnt2d[(size_t)i * NBLK1 + blockIdx.x] = lcount[i];
}

__global__ __launch_bounds__(256) void k2_colscan_kernel(int* __restrict__ cnt2d,
                                                         int* __restrict__ cbase)
{
    __shared__ int sv[256];
    int t = threadIdx.x;
    int* col = cnt2d + (size_t)blockIdx.x * NBLK1;
    int a[3]; int s = 0;
    #pragma unroll
    for (int k = 0; k < 3; ++k) {
        int i = t * 3 + k;
        a[k] = (i < NBLK1) ? col[i] : 0;
        s += a[k];
    }
    sv[t] = s; __syncthreads();
    for (int off = 1; off < 256; off <<= 1) {
        int v = (t >= off) ? sv[t - off] : 0; __syncthreads();
        sv[t] += v; __syncthreads();
    }
    int excl = sv[t] - s;
    #pragma unroll
    for (int k = 0; k < 3; ++k) {
        int i = t * 3 + k;
        if (i < NBLK1) { col[i] = excl; excl += a[k]; }
    }
    if (t == 255) cbase[blockIdx.x] = sv[255];
}

__global__ __launch_bounds__(256) void k3_cscan_kernel(int* __restrict__ cbase,
                                                       int* __restrict__ P)
{
    __shared__ int sv[256];
    int t = threadIdx.x;
    int a[3]; int s = 0;
    #pragma unroll
    for (int k = 0; k < 3; ++k) {
        int i = t * 3 + k;
        a[k] = (i < NCB) ? cbase[i] : 0;
        s += a[k];
    }
    sv[t] = s; __syncthreads();
    for (int off = 1; off < 256; off <<= 1) {
        int v = (t >= off) ? sv[t - off] : 0; __syncthreads();
        sv[t] += v; __syncthreads();
    }
    int excl = sv[t] - s;
    #pragma unroll
    for (int k = 0; k < 3; ++k) {
        int i = t * 3 + k;
        if (i < NCB) { cbase[i] = excl; excl += a[k]; }
    }
    if (t == 255) { cbase[NCB] = sv[255]; P[NROWS] = sv[255]; }
}

__global__ __launch_bounds__(256) void part1_kernel(const int* __restrict__ edges,
                                                    const int* __restrict__ cnt2d,
                                                    const int* __restrict__ cbase,
                                                    unsigned* __restrict__ buf)
{
    __shared__ int lcur[NCB];
    for (int i = threadIdx.x; i < NCB; i += 256)
        lcur[i] = cbase[i] + cnt2d[(size_t)i * NBLK1 + blockIdx.x];
    __syncthreads();
    int g0 = blockIdx.x * TILE1;
    #pragma unroll 4
    for (int k = 0; k < TILE1 / 256; ++k) {
        int g = g0 + k * 256 + threadIdx.x;
        if (g < 7 * NEDGE) {
            int t = g / NEDGE, i = g - t * NEDGE;
            int s = edges[(size_t)t * 2 * NEDGE + i];
            int d = edges[(size_t)t * 2 * NEDGE + NEDGE + i];
            int r = t * N_NODES + d;
            int pos = atomicAdd(&lcur[r >> 9], 1);
            buf[pos] = ((unsigned)(r & 511) << 16) | (unsigned)s;
        }
    }
}

__global__ __launch_bounds__(256) void part2_kernel(const unsigned* __restrict__ buf,
                                                    const int* __restrict__ cbase,
                                                    int* __restrict__ P,
                                                    int* __restrict__ col_src)
{
    __shared__ int fcnt[CROWS];
    __shared__ int fpos[CROWS];
    __shared__ int sv[256];
    int b = blockIdx.x;
    int t = threadIdx.x;
    int start = cbase[b], end = cbase[b + 1];
    fcnt[2 * t] = 0; fcnt[2 * t + 1] = 0;
    __syncthreads();
    for (int i = start + t; i < end; i += 256)
        atomicAdd(&fcnt[buf[i] >> 16], 1);
    __syncthreads();
    int a0 = fcnt[2 * t], a1 = fcnt[2 * t + 1];
    int s = a0 + a1;
    sv[t] = s; __syncthreads();
    for (int off = 1; off < 256; off <<= 1) {
        int v = (t >= off) ? sv[t - off] : 0; __syncthreads();
        sv[t] += v; __syncthreads();
    }
    int excl = sv[t] - s;
    fpos[2 * t] = excl; fpos[2 * t + 1] = excl + a0;
    int r0 = b * CROWS;
    int rows_in = NROWS - r0; if (rows_in > CROWS) rows_in = CROWS;
    if (2 * t < rows_in)     P[r0 + 2 * t]     = start + excl;
    if (2 * t + 1 < rows_in) P[r0 + 2 * t + 1] = start + excl + a0;
    __syncthreads();
    for (int i = start + t; i < end; i += 256) {
        unsigned v = buf[i];
        int pos = start + atomicAdd(&fpos[v >> 16], 1);
        col_src[pos] = (int)(v & 0xffffu);
    }
}

// ---------------- fallback CSR build (ws-limited) ----------------

__global__ __launch_bounds__(256) void hist_kernel(const int* __restrict__ edges,
                                                   int* __restrict__ cnt, int ntypes)
{
    int g = blockIdx.x * 256 + threadIdx.x;
    if (g >= ntypes * NEDGE) return;
    int t = g / NEDGE, i = g - t * NEDGE;
    int d = edges[(size_t)t * 2 * NEDGE + NEDGE + i];
    atomicAdd(&cnt[t * N_NODES + d], 1);
}

__global__ __launch_bounds__(256) void scanA_kernel(const int* __restrict__ cnt,
                                                    int* __restrict__ bsums, int n)
{
    __shared__ int lds[256];
    int tid = threadIdx.x;
    int base = blockIdx.x * 2048 + tid * 8;
    int s = 0;
    #pragma unroll
    for (int k = 0; k < 8; ++k) { int i = base + k; if (i < n) s += cnt[i]; }
    lds[tid] = s;
    __syncthreads();
    for (int o = 128; o > 0; o >>= 1) {
        if (tid < o) lds[tid] += lds[tid + o];
        __syncthreads();
    }
    if (tid == 0) bsums[blockIdx.x] = lds[0];
}

__global__ __launch_bounds__(256) void scanB_kernel(const int* __restrict__ bsums,
                                                    int* __restrict__ boffs, int nb,
                                                    int* __restrict__ P, int n)
{
    __shared__ int lds[256];
    int tid = threadIdx.x;
    int v = (tid < nb) ? bsums[tid] : 0;
    lds[tid] = v;
    __syncthreads();
    for (int off = 1; off < 256; off <<= 1) {
        int t2 = (tid >= off) ? lds[tid - off] : 0;
        __syncthreads();
        lds[tid] += t2;
        __syncthreads();
    }
    if (tid < nb) boffs[tid] = lds[tid] - v;
    if (tid == 255) P[n] = lds[255];
}

__global__ __launch_bounds__(256) void scanC_kernel(const int* __restrict__ cnt,
                                                    const int* __restrict__ boffs,
                                                    int* __restrict__ P,
                                                    int* __restrict__ cursor, int n)
{
    __shared__ int lds[256];
    int tid = threadIdx.x;
    int base = blockIdx.x * 2048 + tid * 8;
    int v[8];
    int s = 0;
    #pragma unroll
    for (int k = 0; k < 8; ++k) {
        int i = base + k;
        int c = (i < n) ? cnt[i] : 0;
        v[k] = s;
        s += c;
    }
    lds[tid] = s;
    __syncthreads();
    for (int off = 1; off < 256; off <<= 1) {
        int t2 = (tid >= off) ? lds[tid - off] : 0;
        __syncthreads();
        lds[tid] += t2;
        __syncthreads();
    }
    int off0 = boffs[blockIdx.x] + (lds[tid] - s);
    #pragma unroll
    for (int k = 0; k < 8; ++k) {
        int i = base + k;
        if (i < n) { int val = off0 + v[k]; P[i] = val; cursor[i] = val; }
    }
}

__global__ __launch_bounds__(256) void scatter1_kernel(const int* __restrict__ et,
                                                       int* __restrict__ cursor,
                                                       int* __restrict__ col_src)
{
    int i = blockIdx.x * 256 + threadIdx.x;
    if (i >= NEDGE) return;
    int s = et[i], d = et[NEDGE + i];
    int pos = atomicAdd(&cursor[d], 1);
    col_src[pos] = s;
}

// ---------------- linear transforms: weights in registers ----------------
// Thread owns output column h for 8 nodes; W[:,h] filled into 32/64 VGPRs via
// coalesced L2-resident loads (lane h -> consecutive addresses).

__global__ __launch_bounds__(256) void lin_d32_kernel(
    const void* fLb, const void* fLf, const void* fRb, const void* fRf,
    const void* wLb, const void* wLf, const void* wRb, const void* wRf,
    const void* bLb, const void* bLf, const void* bRb, const void* bRf,
    const int* __restrict__ flag, float* __restrict__ xl, float* __restrict__ xr)
{
    int bf = flag[0];
    int side = blockIdx.y;
    const void* W    = side ? (bf ? wRb : wRf) : (bf ? wLb : wLf);
    const void* b    = side ? (bf ? bRb : bRf) : (bf ? bLb : bLf);
    const void* feat = side ? (bf ? fRb : fRf) : (bf ? fLb : fLf);
    float* out = side ? xr : xl;
    int tid = threadIdx.x;
    int h = tid & 63;
    int slot = tid >> 6;

    float w[DIN];
    float bias;
    if (bf) {
        const bf16* Wb = (const bf16*)W;
        #pragma unroll
        for (int d = 0; d < DIN; ++d) w[d] = __bfloat162float(Wb[d * HDIM + h]);
        bias = __bfloat162float(((const bf16*)b)[h]);
    } else {
        const float* Wf = (const float*)W;
        #pragma unroll
        for (int d = 0; d < DIN; ++d) w[d] = Wf[d * HDIM + h];
        bias = ((const float*)b)[h];
    }

    int base = blockIdx.x * 32;
    #pragma unroll
    for (int nn = 0; nn < 8; ++nn) {
        int node = base + nn * 4 + slot;
        if (node >= N_NODES) break;
        float acc = bias;
        if (bf) {
            const bf16* f = (const bf16*)feat + (size_t)node * DIN;
            #pragma unroll
            for (int d = 0; d < DIN; ++d) acc += __bfloat162float(f[d]) * w[d];
        } else {
            const float4* f4 = (const float4*)((const float*)feat + (size_t)node * DIN);
            #pragma unroll
            for (int k = 0; k < DIN / 4; ++k) {
                float4 a = f4[k];
                acc += a.x * w[4*k] + a.y * w[4*k+1] + a.z * w[4*k+2] + a.w * w[4*k+3];
            }
        }
        out[(size_t)node * HDIM + h] = acc;
    }
}

__global__ __launch_bounds__(256) void lin_d64_kernel(
    const float* __restrict__ fL, const float* __restrict__ fR,
    const void* wLb, const void* wLf, const void* wRb, const void* wRf,
    const void* bLb, const void* bLf, const void* bRb, const void* bRf,
    const int* __restrict__ flag, float* __restrict__ xl, float* __restrict__ xr)
{
    int bf = flag[0];
    int side = blockIdx.y;
    const void* W = side ? (bf ? wRb : wRf) : (bf ? wLb : wLf);
    const void* b = side ? (bf ? bRb : bRf) : (bf ? bLb : bLf);
    const float* feat = side ? fR : fL;
    float* out = side ? xr : xl;
    int tid = threadIdx.x;
    int h = tid & 63;
    int slot = tid >> 6;

    float w[HDIM];
    float bias;
    if (bf) {
        const bf16* Wb = (const bf16*)W;
        #pragma unroll
        for (int d = 0; d < HDIM; ++d) w[d] = __bfloat162float(Wb[d * HDIM + h]);
        bias = __bfloat162float(((const bf16*)b)[h]);
    } else {
        const float* Wf = (const float*)W;
        #pragma unroll
        for (int d = 0; d < HDIM; ++d) w[d] = Wf[d * HDIM + h];
        bias = ((const float*)b)[h];
    }

    int base = blockIdx.x * 32;
    #pragma unroll
    for (int nn = 0; nn < 8; ++nn) {
        int node = base + nn * 4 + slot;
        if (node >= N_NODES) break;
        const float4* f4 = (const float4*)(feat + (size_t)node * HDIM);
        float acc = bias;
        #pragma unroll
        for (int k = 0; k < 16; ++k) {
            float4 a = f4[k];
            acc += a.x * w[4*k] + a.y * w[4*k+1] + a.z * w[4*k+2] + a.w * w[4*k+3];
        }
        out[(size_t)node * HDIM + h] = acc;
    }
}

// ---------------- fused GATv2 attention: subgroup-parallel ----------------
__global__ __launch_bounds__(256) void gat_row_kernel(
    const int* __restrict__ rowptr, const int* __restrict__ col_src,
    const float* __restrict__ xl, const float* __restrict__ xr,
    const void* ab, const void* af, const int* __restrict__ flag,
    float* __restrict__ hn, int init)
{
    int bf = flag[0];
    const void* att = bf ? ab : af;
    int wave = threadIdx.x >> 6;
    int lane = threadIdx.x & 63;
    int d = blockIdx.x * 4 + wave;
    if (d >= N_NODES) return;
    int rs = rowptr[d], re = rowptr[d + 1];

    int g = lane >> 4;
    int c = lane & 15;

    if (re <= rs) {
        if (init && g == 0)
            ((float4*)(hn + (size_t)d * HDIM))[c] = make_float4(0.f, 0.f, 0.f, 0.f);
        return;
    }

    float4 attv;
    attv.x = ldf(att, 4*c + 0, bf);
    attv.y = ldf(att, 4*c + 1, bf);
    attv.z = ldf(att, 4*c + 2, bf);
    attv.w = ldf(att, 4*c + 3, bf);
    float4 xrv = ((const float4*)(xr + (size_t)d * HDIM))[c];

    float4 acc = make_float4(0.f, 0.f, 0.f, 0.f);
    float m = -1e30f, s = 0.f;

    for (int cs0 = rs; cs0 < re; cs0 += 16) {
        float e[4];
        float4 xlv[4];
        #pragma unroll
        for (int it = 0; it < 4; ++it) {
            int ei = cs0 + it * 4 + g;
            bool valid = ei < re;
            float4 xv = make_float4(0.f, 0.f, 0.f, 0.f);
            if (valid) {
                int src = col_src[ei];
                xv = ((const float4*)(xl + (size_t)src * HDIM))[c];
            }
            xlv[it] = xv;
            float vx = xv.x + xrv.x; vx = vx > 0.f ? vx : 0.2f * vx;
            float vy = xv.y + xrv.y; vy = vy > 0.f ? vy : 0.2f * vy;
            float vz = xv.z + xrv.z; vz = vz > 0.f ? vz : 0.2f * vz;
            float vw = xv.w + xrv.w; vw = vw > 0.f ? vw : 0.2f * vw;
            float t = attv.x * vx + attv.y * vy + attv.z * vz + attv.w * vw;
            t += __shfl_xor(t, 1, 64);
            t += __shfl_xor(t, 2, 64);
            t += __shfl_xor(t, 4, 64);
            t += __shfl_xor(t, 8, 64);
            e[it] = valid ? t : -1e30f;
        }
        float cm = fmaxf(fmaxf(e[0], e[1]), fmaxf(e[2], e[3]));
        cm = fmaxf(cm, __shfl_xor(cm, 16, 64));
        cm = fmaxf(cm, __shfl_xor(cm, 32, 64));
        if (cm > m) {
            float sc = __expf(m - cm);
            s *= sc;
            acc.x *= sc; acc.y *= sc; acc.z *= sc; acc.w *= sc;
            m = cm;
        }
        #pragma unroll
        for (int it = 0; it < 4; ++it) {
            float w = __expf(e[it] - m);
            s += w;
            acc.x += w * xlv[it].x;
            acc.y += w * xlv[it].y;
            acc.z += w * xlv[it].z;
            acc.w += w * xlv[it].w;
        }
    }
    acc.x += __shfl_xor(acc.x, 16, 64); acc.x += __shfl_xor(acc.x, 32, 64);
    acc.y += __shfl_xor(acc.y, 16, 64); acc.y += __shfl_xor(acc.y, 32, 64);
    acc.z += __shfl_xor(acc.z, 16, 64); acc.z += __shfl_xor(acc.z, 32, 64);
    acc.w += __shfl_xor(acc.w, 16, 64); acc.w += __shfl_xor(acc.w, 32, 64);
    s += __shfl_xor(s, 16, 64); s += __shfl_xor(s, 32, 64);

    if (g == 0) {
        float inv = 1.f / (s + 1e-16f);
        float4* op = (float4*)(hn + (size_t)d * HDIM);
        if (init) {
            op[c] = make_float4(acc.x * inv, acc.y * inv, acc.z * inv, acc.w * inv);
        } else {
            float4 old = op[c];
            op[c] = make_float4(old.x + acc.x * inv, old.y + acc.y * inv,
                                old.z + acc.z * inv, old.w + acc.w * inv);
        }
    }
}

// ---------------- epilogue ----------------

__global__ void bsum_kernel(const void* __restrict__ bias, const int* __restrict__ flag,
                            float* __restrict__ bsum)
{
    int bf = flag[0];
    int idx = threadIdx.x;  // 192 = 3*64
    if (idx >= 192) return;
    int nt = idx >> 6, h = idx & 63;
    float v;
    if (nt == 0)      v = ldf(bias, 0*64+h, bf) + ldf(bias, 1*64+h, bf) + ldf(bias, 4*64+h, bf);
    else if (nt == 1) v = ldf(bias, 2*64+h, bf) + ldf(bias, 5*64+h, bf);
    else              v = ldf(bias, 3*64+h, bf) + ldf(bias, 6*64+h, bf);
    bsum[idx] = v;
}

__global__ __launch_bounds__(256) void relu_kernel(
    const float* __restrict__ hn, const float* __restrict__ bsum,
    float* __restrict__ h)
{
    size_t idx = (size_t)blockIdx.x * 256 + threadIdx.x;
    if (idx >= (size_t)3 * N_NODES * HDIM) return;
    int nt = (int)(idx / ((size_t)N_NODES * HDIM));
    int hh = (int)(idx & 63);
    float v = hn[idx] + bsum[nt * 64 + hh];
    h[idx] = v > 0.f ? v : 0.f;
}

__global__ __launch_bounds__(256) void head_kernel(
    const float* __restrict__ h0, const void* __restrict__ Wout,
    const void* __restrict__ bout, const int* __restrict__ flag,
    void* __restrict__ out)
{
    __shared__ float sW[64 * 4];
    __shared__ float sb[4];
    int bf = flag[0];
    int tid = threadIdx.x;
    sW[tid] = ldf(Wout, tid, bf);
    if (tid < 4) sb[tid] = ldf(bout, tid, bf);
    __syncthreads();
    int i = blockIdx.x * 256 + tid;
    if (i >= N_NODES) return;
    float l0 = sb[0], l1 = sb[1], l2 = sb[2], l3 = sb[3];
    const float4* p = (const float4*)(h0 + (size_t)i * HDIM);
    #pragma unroll
    for (int k = 0; k < 16; ++k) {
        float4 a = p[k];
        int d = 4 * k;
        l0 += a.x * sW[d*4+0] + a.y * sW[(d+1)*4+0] + a.z * sW[(d+2)*4+0] + a.w * sW[(d+3)*4+0];
        l1 += a.x * sW[d*4+1] + a.y * sW[(d+1)*4+1] + a.z * sW[(d+2)*4+1] + a.w * sW[(d+3)*4+1];
        l2 += a.x * sW[d*4+2] + a.y * sW[(d+1)*4+2] + a.z * sW[(d+2)*4+2] + a.w * sW[(d+3)*4+2];
        l3 += a.x * sW[d*4+3] + a.y * sW[(d+1)*4+3] + a.z * sW[(d+2)*4+3] + a.w * sW[(d+3)*4+3];
    }
    float m = fmaxf(fmaxf(l0, l1), fmaxf(l2, l3));
    float e0 = __expf(l0 - m), e1 = __expf(l1 - m), e2 = __expf(l2 - m), e3 = __expf(l3 - m);
    float inv = 1.f / (e0 + e1 + e2 + e3);
    if (bf) {
        bf16* o = (bf16*)out;
        o[(size_t)4*i + 0] = __float2bfloat16(e0 * inv);
        o[(size_t)4*i + 1] = __float2bfloat16(e1 * inv);
        o[(size_t)4*i + 2] = __float2bfloat16(e2 * inv);
        o[(size_t)4*i + 3] = __float2bfloat16(e3 * inv);
    } else {
        float* o = (float*)out;
        o[(size_t)4*i + 0] = e0 * inv;
        o[(size_t)4*i + 1] = e1 * inv;
        o[(size_t)4*i + 2] = e2 * inv;
        o[(size_t)4*i + 3] = e3 * inv;
    }
}

struct P2 { const void* b; const void* f; };
static inline P2 off2(const void* base, size_t elem) {
    P2 r;
    r.b = (const void*)((const bf16*)base + elem);
    r.f = (const void*)((const float*)base + elem);
    return r;
}

extern "C" void kernel_launch(void* const* d_in, const int* in_sizes, int n_in,
                              void* d_out, int out_size, void* d_ws, size_t ws_size,
                              hipStream_t stream)
{
    const void* x     = d_in[0];
    const int*  edges = (const int*)d_in[1];
    const void* Wl0 = d_in[2];
    const void* Wr0 = d_in[3];
    const void* bl0 = d_in[4];
    const void* br0 = d_in[5];
    const void* att0 = d_in[6];
    const void* bias0 = d_in[7];
    const void* Wl1 = d_in[8];
    const void* Wr1 = d_in[9];
    const void* bl1 = d_in[10];
    const void* br1 = d_in[11];
    const void* att1 = d_in[12];
    const void* bias1 = d_in[13];
    const void* Wout = d_in[14];
    const void* bout = d_in[15];

    const int SRCt[7] = {0, 1, 1, 1, 2, 2, 2};
    const int DSTt[7] = {0, 0, 1, 2, 0, 1, 2};

    // ---- workspace layout ----
    float* h3  = (float*)d_ws;                                  // 3*N*H
    float* hn3 = h3 + (size_t)3 * N_NODES * HDIM;               // 3*N*H (38.4 MB)
    float* xl  = hn3 + (size_t)3 * N_NODES * HDIM;              // N*H
    float* xr  = xl + (size_t)N_NODES * HDIM;                   // N*H
    char* tail = (char*)(xr + (size_t)N_NODES * HDIM);

    size_t fixed = (size_t)tail - (size_t)d_ws;
    size_t need_full = fixed + ((size_t)NROWS + 1) * 4 + (size_t)7 * NEDGE * 4
                     + (NCB + 1) * 4 + 2 * 256 * 4 + 192 * 4 + 4
                     + 2 * (size_t)N_NODES * 4 + 256;
    bool full = ws_size >= need_full;
    int NT = full ? 7 : 1;

    int* P        = (int*)tail;                                 // NT*N+1
    int* col_src  = P + ((size_t)NT * N_NODES + 1);             // NT*E
    int* cbase    = col_src + (size_t)NT * NEDGE;               // NCB+1
    int* bsums    = cbase + (NCB + 1);                          // 256
    int* boffs    = bsums + 256;                                // 256
    float* bsum   = (float*)(boffs + 256);                      // 192
    int* flag     = (int*)(bsum + 192);                         // 1
    int* cnt      = flag + 1;                                   // N (fallback)
    int* cursor   = cnt + N_NODES;                              // N (fallback)

    unsigned* buf = (unsigned*)hn3;                             // 7E (22.4 MB)
    int* cnt2d    = (int*)(buf + (size_t)7 * NEDGE);            // NCB*NBLK1 (1.87 MB)

    dim3 blk(256);
    int gLin  = (N_NODES + 31) / 32;                            // 1563
    int gRow  = (N_NODES + 3) / 4;
    int gRelu = (int)(((size_t)3 * N_NODES * HDIM + 255) / 256);
    int gHead = (N_NODES + 255) / 256;

    detect_kernel<<<1, 256, 0, stream>>>((const unsigned short*)x, flag);

    if (full) {
        k1_count_kernel<<<NBLK1, blk, 0, stream>>>(edges, cnt2d);
        k2_colscan_kernel<<<NCB, blk, 0, stream>>>(cnt2d, cbase);
        k3_cscan_kernel<<<1, blk, 0, stream>>>(cbase, P);
        part1_kernel<<<NBLK1, blk, 0, stream>>>(edges, cnt2d, cbase, buf);
        part2_kernel<<<NCB, blk, 0, stream>>>(buf, cbase, P, col_src);
    }

    for (int layer = 0; layer < 2; ++layer) {
        const void* Wl = layer ? Wl1 : Wl0;
        const void* Wr = layer ? Wr1 : Wr0;
        const void* bl = layer ? bl1 : bl0;
        const void* br = layer ? br1 : br0;
        const void* at = layer ? att1 : att0;
        const void* bi = layer ? bias1 : bias0;

        bsum_kernel<<<1, 192, 0, stream>>>(bi, flag, bsum);

        for (int t = 0; t < 7; ++t) {
            const int* rp;
            const int* cs;
            if (full) {
                rp = P + (size_t)t * N_NODES;
                cs = col_src;
            } else {
                const int* et = edges + (size_t)t * 2 * NEDGE;
                int n = N_NODES;
                int nb = (n + 2047) / 2048;
                int gE1 = (NEDGE + 255) / 256;
                hipMemsetAsync(cnt, 0, (size_t)n * sizeof(int), stream);
                hist_kernel<<<gE1, blk, 0, stream>>>(et, cnt, 1);
                scanA_kernel<<<nb, blk, 0, stream>>>(cnt, bsums, n);
                scanB_kernel<<<1, blk, 0, stream>>>(bsums, boffs, nb, P, n);
                scanC_kernel<<<nb, blk, 0, stream>>>(cnt, boffs, P, cursor, n);
                scatter1_kernel<<<gE1, blk, 0, stream>>>(et, cursor, col_src);
                rp = P;
                cs = col_src;
            }

            if (layer == 0) {
                P2 fs = off2(x, (size_t)SRCt[t] * N_NODES * DIN);
                P2 fd = off2(x, (size_t)DSTt[t] * N_NODES * DIN);
                P2 wl = off2(Wl, (size_t)t * DIN * HDIM);
                P2 wr = off2(Wr, (size_t)t * DIN * HDIM);
                P2 bL = off2(bl, (size_t)t * HDIM);
                P2 bR = off2(br, (size_t)t * HDIM);
                lin_d32_kernel<<<dim3(gLin, 2), blk, 0, stream>>>(
                    fs.b, fs.f, fd.b, fd.f, wl.b, wl.f, wr.b, wr.f,
                    bL.b, bL.f, bR.b, bR.f, flag, xl, xr);
            } else {
                P2 wl = off2(Wl, (size_t)t * HDIM * HDIM);
                P2 wr = off2(Wr, (size_t)t * HDIM * HDIM);
                P2 bL = off2(bl, (size_t)t * HDIM);
                P2 bR = off2(br, (size_t)t * HDIM);
                lin_d64_kernel<<<dim3(gLin, 2), blk, 0, stream>>>(
                    h3 + (size_t)SRCt[t] * N_NODES * HDIM,
                    h3 + (size_t)DSTt[t] * N_NODES * HDIM,
                    wl.b, wl.f, wr.b, wr.f, bL.b, bL.f, bR.b, bR.f, flag, xl, xr);
            }

            int init = (t == 0 || t == 2 || t == 3) ? 1 : 0;
            P2 a2 = off2(at, (size_t)t * HDIM);
            gat_row_kernel<<<gRow, blk, 0, stream>>>(rp, cs, xl, xr,
                                                     a2.b, a2.f, flag,
                                                     hn3 + (size_t)DSTt[t] * N_NODES * HDIM,
                                                     init);
        }
        relu_kernel<<<gRelu, blk, 0, stream>>>(hn3, bsum, h3);
    }

    head_kernel<<<gHead, blk, 0, stream>>>(h3, Wout, bout, flag, d_out);
}